// Round 9
// baseline (430.291 us; speedup 1.0000x reference)
//
#include <hip/hip_runtime.h>
#include <math.h>

#define NN 50000
#define NE 800000
#define IN_DIM 128
#define HID 256
#define OUT_DIM 40
#define BN_EPS 1e-5f

#define HG 128          // histogram blocks (col-degree)
#define HW 25000        // packed words (2 nodes/word)
#define HPASS 12800     // words per LDS pass

#define NBK 196         // row buckets (256 rows each)
#define PB 256          // partition blocks
#define EPB (NE / PB)   // 3125 edges per partition block

typedef __attribute__((ext_vector_type(8))) short short8;
typedef __attribute__((ext_vector_type(4))) float f32x4;
typedef __attribute__((ext_vector_type(2))) float f32x2;

__device__ __forceinline__ ushort f2bf(float f) {
    union { float f; unsigned u; } v; v.f = f;
    unsigned r = v.u + 0x7fffu + ((v.u >> 16) & 1u);
    return (ushort)(r >> 16);
}
__device__ __forceinline__ float bflo(unsigned u) {
    union { unsigned a; float f; } v; v.a = u << 16; return v.f;
}
__device__ __forceinline__ float bfhi(unsigned u) {
    union { unsigned a; float f; } v; v.a = u & 0xffff0000u; return v.f;
}
// fp8 e4m3 (OCP) via HW converts — word-select must be a literal constant
__device__ __forceinline__ f32x2 fp8_dec_lo(int v) {
    return __builtin_amdgcn_cvt_pk_f32_fp8(v, false);
}
__device__ __forceinline__ int fp8_enc_lo(float a, float b, int old) {
    return __builtin_amdgcn_cvt_pk_fp8_f32(a, b, old, false);
}
__device__ __forceinline__ int fp8_enc_hi(float a, float b, int old) {
    return __builtin_amdgcn_cvt_pk_fp8_f32(a, b, old, true);
}
__device__ __forceinline__ float fp8_dec1(int byte) {  // single fp8 byte -> float
    f32x2 f = fp8_dec_lo(byte & 0xff);
    return f[0];
}

// ================ P1: col-degree LDS histogram (blocks 0..HG) + row-bucket counts (HG..HG+PB) ================
__global__ __launch_bounds__(512) void k_p1(const int* __restrict__ erow,
                                            const int* __restrict__ ecol,
                                            unsigned* __restrict__ Pcol,
                                            unsigned* __restrict__ cnt) {
    __shared__ unsigned lds[HPASS];
    int t = threadIdx.x;
    int b = blockIdx.x;
    if (b < HG) {
        unsigned* partial = Pcol + (size_t)b * HW;
        int e0 = b * (NE / HG), e1 = e0 + (NE / HG);
#pragma unroll
        for (int pass = 0; pass < 2; pass++) {
            int wbase = pass ? HPASS : 0;
            int wend = pass ? HW : HPASS;
            int nw = wend - wbase;
            for (int w = t; w < HPASS; w += 512) lds[w] = 0u;
            __syncthreads();
            int vlo = wbase * 2, vhi = wend * 2;
            for (int e = e0 + t; e < e1; e += 512) {
                int v = ecol[e];
                if (v >= vlo && v < vhi)
                    atomicAdd(&lds[(v >> 1) - wbase], (v & 1) ? 0x10000u : 1u);
            }
            __syncthreads();
            for (int w = t; w < nw; w += 512) partial[wbase + w] = lds[w];
            __syncthreads();
        }
    } else {
        int bb = b - HG;
        for (int i = t; i < NBK; i += 512) lds[i] = 0u;
        __syncthreads();
        int e0 = bb * EPB;
        for (int i = t; i < EPB; i += 512) atomicAdd(&lds[((unsigned)erow[e0 + i]) >> 8], 1u);
        __syncthreads();
        for (int i = t; i < NBK; i += 512) cnt[bb * NBK + i] = lds[i];
    }
}

// ================ P2: hist reduce -> dinv (blocks 0..97) + bucket scan/offsets (block 98) ================
__global__ __launch_bounds__(256) void k_p2(const unsigned* __restrict__ Pcol,
                                            float* __restrict__ dinv,
                                            const unsigned* __restrict__ cnt,
                                            unsigned* __restrict__ off,
                                            unsigned* __restrict__ bstart) {
    int t = threadIdx.x;
    if (blockIdx.x < 98) {
        int w = blockIdx.x * 256 + t;
        if (w >= HW) return;
        unsigned sc = 0;
        for (int b = 0; b < HG; b++) sc += Pcol[(size_t)b * HW + w];
        dinv[2 * w] = rsqrtf((float)((sc & 0xffffu) + 1u));
        dinv[2 * w + 1] = rsqrtf((float)((sc >> 16) + 1u));
    } else {
        __shared__ unsigned s[256];
        unsigned tot = 0;
        if (t < NBK) for (int b = 0; b < PB; b++) tot += cnt[b * NBK + t];
        s[t] = tot;
        __syncthreads();
        for (int o = 1; o < 256; o <<= 1) {
            unsigned x = (t >= o) ? s[t - o] : 0u;
            __syncthreads();
            s[t] += x;
            __syncthreads();
        }
        unsigned base = s[t] - tot;
        if (t < NBK) bstart[t] = base;
        if (t == NBK - 1) bstart[NBK] = base + tot;
        if (t < NBK) {
            unsigned run = base;
            for (int b = 0; b < PB; b++) { off[b * NBK + t] = run; run += cnt[b * NBK + t]; }
        }
    }
}

// ================ P3: edge scatter into buckets (blocks 0..PB) + input prep (rest) ================
// xs8 is column-sliced: [slice=col/32][row][32]
__global__ __launch_bounds__(256) void k_p3(const int* __restrict__ erow,
                                            const int* __restrict__ ecol,
                                            const unsigned* __restrict__ off,
                                            int2* __restrict__ ebuf,
                                            const float* __restrict__ x,
                                            const float* __restrict__ dinv,
                                            uchar* __restrict__ xs8,
                                            const float* __restrict__ W1,
                                            const float* __restrict__ W2,
                                            const float* __restrict__ W3,
                                            ushort* __restrict__ Wt1,
                                            ushort* __restrict__ Wt2,
                                            ushort* __restrict__ Wt3) {
    int t = threadIdx.x, b = blockIdx.x;
    if (b < PB) {
        __shared__ unsigned c[NBK];
        for (int i = t; i < NBK; i += 256) c[i] = off[b * NBK + i];
        __syncthreads();
        int e0 = b * EPB;
        for (int i = t; i < EPB; i += 256) {
            int r = erow[e0 + i], cc = ecol[e0 + i];
            unsigned p = atomicAdd(&c[((unsigned)r) >> 8], 1u);
            ebuf[p] = make_int2(r, cc);
        }
    } else if (b < PB + 6250) {
        int i = (b - PB) * 256 + t;   // over N*128/4 = 1.6M exactly
        int row = i >> 5;             // 32 groups of 4 cols per row
        int g = i & 31;
        float d = dinv[row];
        float4 v = ((const float4*)x)[i];
        int p = fp8_enc_lo(v.x * d, v.y * d, 0);
        p = fp8_enc_hi(v.z * d, v.w * d, p);
        int slice = g >> 3;
        ((int*)xs8)[((size_t)slice * NN + row) * 8 + (g & 7)] = p;
    } else {
        int i = (b - PB - 6250) * 256 + t;
        if (i < 128 * 256) { int k = i / 256, n = i % 256; Wt1[n * 128 + k] = f2bf(W1[i]); }
        if (i < 256 * 256) { int k = i / 256, n = i % 256; Wt2[n * 256 + k] = f2bf(W2[i]); }
        if (i < 48 * 256)  { int n = i / 256, k = i % 256;
                             Wt3[i] = (n < OUT_DIM) ? f2bf(W3[k * OUT_DIM + n]) : (ushort)0; }
    }
}

// ================ P4: per-bucket row counts -> rowptr -> colidx fill ================
__global__ __launch_bounds__(256) void k_part4(const int2* __restrict__ ebuf,
                                               const unsigned* __restrict__ bstart,
                                               unsigned* __restrict__ rowptr,
                                               int* __restrict__ colidx) {
    __shared__ unsigned rc[256], cur[256], s[256];
    int t = threadIdx.x, b = blockIdx.x;
    unsigned ebase = bstart[b], ecnt = bstart[b + 1] - ebase;
    rc[t] = 0u;
    __syncthreads();
    for (unsigned i = t; i < ecnt; i += 256) atomicAdd(&rc[ebuf[ebase + i].x & 255], 1u);
    __syncthreads();
    unsigned v = rc[t];
    s[t] = v;
    __syncthreads();
    for (int o = 1; o < 256; o <<= 1) {
        unsigned x = (t >= o) ? s[t - o] : 0u;
        __syncthreads();
        s[t] += x;
        __syncthreads();
    }
    unsigned excl = s[t] - v;
    int row = (b << 8) + t;
    if (row < NN) rowptr[row] = ebase + excl;
    cur[t] = ebase + excl;
    if (b == 0 && t == 0) rowptr[NN] = NE;
    __syncthreads();
    for (unsigned i = t; i < ecnt; i += 256) {
        int2 e = ebuf[ebase + i];
        unsigned p = atomicAdd(&cur[e.x & 255], 1u);
        colidx[p] = e.y;
    }
}

// ================ column-sliced gather-aggregate ================
// T: fp8 sliced [slice][row][32]; Out: bf16 row-major, stride OSTRIDE.
// grid (NSLICE, 6250): slice in x so linear%NSLICE pins slice->XCD; 8 rows/block.
// 64 threads: half-wave per edge (2 edges in flight), 1 fp8 col/lane.
template <int OSTRIDE>
__global__ __launch_bounds__(64) void k_agg_sl(const uchar* __restrict__ T,
                                               const unsigned* __restrict__ rowptr,
                                               const int* __restrict__ colidx,
                                               const float* __restrict__ dinv,
                                               ushort* __restrict__ Out) {
    int s = blockIdx.x;
    int t = threadIdx.x;
    int col = t & 31, half = t >> 5;
    const uchar* Ts = T + (size_t)s * NN * 32;
    int r0 = blockIdx.y * 8;
#pragma unroll 1
    for (int r = r0; r < r0 + 8; r++) {
        unsigned e0 = rowptr[r], e1 = rowptr[r + 1];
        float a = (half == 0) ? fp8_dec1(Ts[(size_t)r * 32 + col]) : 0.f;
        unsigned e = e0 + half;
        for (; e + 6 < e1; e += 8) {
            int c0 = colidx[e], c1 = colidx[e + 2], c2 = colidx[e + 4], c3 = colidx[e + 6];
            float v0 = fp8_dec1(Ts[(size_t)c0 * 32 + col]);
            float v1 = fp8_dec1(Ts[(size_t)c1 * 32 + col]);
            float v2 = fp8_dec1(Ts[(size_t)c2 * 32 + col]);
            float v3 = fp8_dec1(Ts[(size_t)c3 * 32 + col]);
            a += v0 + v1 + v2 + v3;
        }
        for (; e < e1; e += 2) a += fp8_dec1(Ts[(size_t)colidx[e] * 32 + col]);
        a += __shfl_xor(a, 32, 64);
        if (half == 0) Out[(size_t)r * OSTRIDE + s * 32 + col] = f2bf(dinv[r] * a);
    }
}

// ================ MFMA GEMM 1 (+fused BN1 column stats): H16 = Xa @ Wt1^T ================
template <int K>
__global__ __launch_bounds__(256) void k_gemm1(const ushort* __restrict__ A,
                                               const ushort* __restrict__ Bt,
                                               ushort* __restrict__ H16,
                                               float* __restrict__ bnacc) {
    constexpr int BK = 32;
    constexpr int LD = 40;
    __shared__ ushort sA[64 * LD];
    __shared__ ushort sB[128 * LD];
    int t = threadIdx.x;
    int wave = t >> 6, lane = t & 63;
    int quad = lane >> 4, m15 = lane & 15;
    long r0 = (long)blockIdx.x * 64;
    int n0 = blockIdx.y * 128;

    f32x4 acc[8];
#pragma unroll
    for (int i = 0; i < 8; i++) { acc[i][0] = 0.f; acc[i][1] = 0.f; acc[i][2] = 0.f; acc[i][3] = 0.f; }

    for (int k0 = 0; k0 < K; k0 += BK) {
        {
            int row = t >> 2, seg = (t & 3) * 8;
            long gr = r0 + row;
            uint4 v = make_uint4(0, 0, 0, 0);
            if (gr < NN) v = *(const uint4*)(A + gr * K + k0 + seg);
            *(uint4*)(sA + row * LD + seg) = v;
        }
        {
            int n = t >> 1, seg = (t & 1) * 16;
            const uint4* src = (const uint4*)(Bt + (long)(n0 + n) * K + k0 + seg);
            uint4 b0 = src[0], b1 = src[1];
            *(uint4*)(sB + n * LD + seg) = b0;
            *(uint4*)(sB + n * LD + seg + 8) = b1;
        }
        __syncthreads();
        short8 a = *(const short8*)(sA + (wave * 16 + m15) * LD + quad * 8);
#pragma unroll
        for (int ct = 0; ct < 8; ct++) {
            short8 b = *(const short8*)(sB + (ct * 16 + m15) * LD + quad * 8);
            acc[ct] = __builtin_amdgcn_mfma_f32_16x16x32_bf16(a, b, acc[ct], 0, 0, 0);
        }
        __syncthreads();
    }
    long rowbase = r0 + wave * 16 + quad * 4;
#pragma unroll
    for (int ct = 0; ct < 8; ct++) {
        int col = n0 + ct * 16 + m15;
#pragma unroll
        for (int rg = 0; rg < 4; rg++) {
            long gr = rowbase + rg;
            if (gr < NN) H16[gr * 256 + col] = f2bf(acc[ct][rg]);
        }
    }
    // ---- fused BN1 column stats (guard rows are exact zeros) ----
    float* ldsS = (float*)(void*)sA;
    float* ldsQ = (float*)(void*)sB;
#pragma unroll
    for (int ct = 0; ct < 8; ct++) {
        float s = acc[ct][0] + acc[ct][1] + acc[ct][2] + acc[ct][3];
        float q = acc[ct][0] * acc[ct][0] + acc[ct][1] * acc[ct][1]
                + acc[ct][2] * acc[ct][2] + acc[ct][3] * acc[ct][3];
        s += __shfl_xor(s, 16, 64); q += __shfl_xor(q, 16, 64);
        s += __shfl_xor(s, 32, 64); q += __shfl_xor(q, 32, 64);
        if (quad == 0) {
            ldsS[wave * 128 + ct * 16 + m15] = s;
            ldsQ[wave * 128 + ct * 16 + m15] = q;
        }
    }
    __syncthreads();
    {
        int c = t & 127;
        int slice = blockIdx.x & 7;
        float v = (t < 128)
            ? ldsS[c] + ldsS[128 + c] + ldsS[256 + c] + ldsS[384 + c]
            : ldsQ[c] + ldsQ[128 + c] + ldsQ[256 + c] + ldsQ[384 + c];
        atomicAdd(&bnacc[slice * 512 + ((t < 128) ? 0 : 256) + n0 + c], v);
    }
}

// BN scale/shift prologue: reduce 8 slices of bnacc into LDS (256 threads)
__device__ __forceinline__ void bn_prolog(const float* __restrict__ bnacc,
                                          const float* __restrict__ gamma,
                                          const float* __restrict__ beta,
                                          float* __restrict__ bnsc,
                                          float* __restrict__ bnsh, int t) {
    float s = 0.f, q = 0.f;
#pragma unroll
    for (int sl = 0; sl < 8; sl++) {
        s += bnacc[sl * 512 + t];
        q += bnacc[sl * 512 + 256 + t];
    }
    float mu = s * (1.f / NN);
    float var = q * (1.f / NN) - mu * mu;
    float g = gamma[t] * rsqrtf(var + BN_EPS);
    bnsc[t] = g;
    bnsh[t] = beta[t] - mu * g;
}

// BN+ReLU stage of 8 bf16 cols from H16 row into LDS (scale/shift from LDS)
__device__ __forceinline__ void bn_stage8(const ushort* __restrict__ Hrow, bool valid,
                                          const float* __restrict__ bnsc,
                                          const float* __restrict__ bnsh, int col0,
                                          ushort* __restrict__ dst) {
    uint4 hv = make_uint4(0, 0, 0, 0);
    if (valid) hv = *(const uint4*)(Hrow + col0);
    float f[8] = { bflo(hv.x), bfhi(hv.x), bflo(hv.y), bfhi(hv.y),
                   bflo(hv.z), bfhi(hv.z), bflo(hv.w), bfhi(hv.w) };
#pragma unroll
    for (int j = 0; j < 8; j++)
        dst[j] = f2bf(fmaxf(f[j] * bnsc[col0 + j] + bnsh[col0 + j], 0.f));
}

// ================ MFMA GEMM 2: Ys2(fp8, sliced) = fp8( dinv * (relu(bn(H16)) @ Wt2^T) ) ================
__global__ __launch_bounds__(256) void k_gemm2(const ushort* __restrict__ H16,
                                               const float* __restrict__ bnacc,
                                               const float* __restrict__ gamma,
                                               const float* __restrict__ beta,
                                               const ushort* __restrict__ Bt,
                                               const float* __restrict__ dinv,
                                               uchar* __restrict__ Y8) {
    constexpr int K = 256, BK = 32, LD = 40;
    __shared__ ushort sA[64 * LD];
    __shared__ ushort sB[128 * LD];
    __shared__ float bnsc[256], bnsh[256];
    int t = threadIdx.x;
    int wave = t >> 6, lane = t & 63;
    int quad = lane >> 4, m15 = lane & 15;
    long r0 = (long)blockIdx.x * 64;
    int n0 = blockIdx.y * 128;

    bn_prolog(bnacc, gamma, beta, bnsc, bnsh, t);
    __syncthreads();

    f32x4 acc[8];
#pragma unroll
    for (int i = 0; i < 8; i++) { acc[i][0] = 0.f; acc[i][1] = 0.f; acc[i][2] = 0.f; acc[i][3] = 0.f; }

    for (int k0 = 0; k0 < K; k0 += BK) {
        {
            int row = t >> 2, seg = (t & 3) * 8;
            long gr = r0 + row;
            bn_stage8(H16 + gr * 256, gr < NN, bnsc, bnsh, k0 + seg, sA + row * LD + seg);
        }
        {
            int n = t >> 1, seg = (t & 1) * 16;
            const uint4* src = (const uint4*)(Bt + (long)(n0 + n) * K + k0 + seg);
            uint4 b0 = src[0], b1 = src[1];
            *(uint4*)(sB + n * LD + seg) = b0;
            *(uint4*)(sB + n * LD + seg + 8) = b1;
        }
        __syncthreads();
        short8 a = *(const short8*)(sA + (wave * 16 + m15) * LD + quad * 8);
#pragma unroll
        for (int ct = 0; ct < 8; ct++) {
            short8 b = *(const short8*)(sB + (ct * 16 + m15) * LD + quad * 8);
            acc[ct] = __builtin_amdgcn_mfma_f32_16x16x32_bf16(a, b, acc[ct], 0, 0, 0);
        }
        __syncthreads();
    }
    long rowbase = r0 + wave * 16 + quad * 4;
    float dv[4];
#pragma unroll
    for (int rg = 0; rg < 4; rg++) dv[rg] = (rowbase + rg < NN) ? dinv[rowbase + rg] : 0.f;
#pragma unroll
    for (int ct = 0; ct < 8; ct++) {
        int col = n0 + ct * 16 + m15;
        size_t sbase = ((size_t)(col >> 5) * NN) * 32 + (col & 31);
#pragma unroll
        for (int rg = 0; rg < 4; rg++) {
            long gr = rowbase + rg;
            if (gr < NN) {
                int p = fp8_enc_lo(dv[rg] * acc[ct][rg], 0.f, 0);
                Y8[sbase + (size_t)gr * 32] = (uchar)(p & 0xff);
            }
        }
    }
}

// ================ MFMA GEMM 3: Ys3 (stride 64, bf16) = dinv * (relu(bn2(H16)) @ Wt3^T) ================
__global__ __launch_bounds__(256) void k_gemm3(const ushort* __restrict__ H16,
                                               const float* __restrict__ bnacc,
                                               const float* __restrict__ gamma,
                                               const float* __restrict__ beta,
                                               const ushort* __restrict__ Wt3,
                                               const float* __restrict__ dinv,
                                               ushort* __restrict__ Y) {
    constexpr int LD = 264;
    __shared__ ushort sA[64 * LD];
    __shared__ ushort sB[48 * LD];
    __shared__ float bnsc[256], bnsh[256];
    int t = threadIdx.x;
    int wave = t >> 6, lane = t & 63;
    int quad = lane >> 4, m15 = lane & 15;
    long r0 = (long)blockIdx.x * 64;

    bn_prolog(bnacc, gamma, beta, bnsc, bnsh, t);
    __syncthreads();

    for (int idx = t; idx < 48 * 16; idx += 256) {
        int n = idx >> 4, s = (idx & 15) * 16;
        const uint4* src = (const uint4*)(Wt3 + n * 256 + s);
        *(uint4*)(sB + n * LD + s) = src[0];
        *(uint4*)(sB + n * LD + s + 8) = src[1];
    }
    {
        int row = t >> 2;
        long gr = r0 + row;
#pragma unroll
        for (int s8 = 0; s8 < 8; s8++) {
            int seg = s8 * 32 + (t & 3) * 8;
            bn_stage8(H16 + gr * 256, gr < NN, bnsc, bnsh, seg, sA + row * LD + seg);
        }
    }
    __syncthreads();

    f32x4 acc[3];
#pragma unroll
    for (int i = 0; i < 3; i++) { acc[i][0] = 0.f; acc[i][1] = 0.f; acc[i][2] = 0.f; acc[i][3] = 0.f; }
#pragma unroll
    for (int k0 = 0; k0 < 256; k0 += 32) {
        short8 a = *(const short8*)(sA + (wave * 16 + m15) * LD + k0 + quad * 8);
#pragma unroll
        for (int ct = 0; ct < 3; ct++) {
            short8 b = *(const short8*)(sB + (ct * 16 + m15) * LD + k0 + quad * 8);
            acc[ct] = __builtin_amdgcn_mfma_f32_16x16x32_bf16(a, b, acc[ct], 0, 0, 0);
        }
    }
    long rowbase = r0 + wave * 16 + quad * 4;
#pragma unroll
    for (int ct = 0; ct < 3; ct++) {
        int col = ct * 16 + m15;
#pragma unroll
        for (int rg = 0; rg < 4; rg++) {
            long gr = rowbase + rg;
            if (gr < NN) Y[gr * 64 + col] = f2bf(dinv[gr] * acc[ct][rg]);
        }
    }
}

// ================ layer-3 aggregation + bias + log_softmax ================
__global__ __launch_bounds__(64) void k_agg_lsm(const ushort* __restrict__ Y,
                                                const unsigned* __restrict__ rowptr,
                                                const int* __restrict__ colidx,
                                                const float* __restrict__ dinv,
                                                const float* __restrict__ b3,
                                                float* __restrict__ out) {
    int r = blockIdx.x;
    int t = threadIdx.x;
    bool act = t < OUT_DIM;
    float acc = act ? bflo((unsigned)Y[(size_t)r * 64 + t]) : 0.f;
    unsigned e0 = rowptr[r], e1 = rowptr[r + 1];
    unsigned e = e0;
    for (; e + 4 <= e1; e += 4) {
        int c0 = colidx[e], c1 = colidx[e + 1], c2 = colidx[e + 2], c3 = colidx[e + 3];
        if (act) {
            acc += bflo((unsigned)Y[(size_t)c0 * 64 + t]) + bflo((unsigned)Y[(size_t)c1 * 64 + t])
                 + bflo((unsigned)Y[(size_t)c2 * 64 + t]) + bflo((unsigned)Y[(size_t)c3 * 64 + t]);
        }
    }
    for (; e < e1; e++) {
        if (act) acc += bflo((unsigned)Y[(size_t)colidx[e] * 64 + t]);
    }
    float o = act ? (dinv[r] * acc + b3[t]) : 0.f;
    float m = act ? o : -1e30f;
#pragma unroll
    for (int d = 1; d < 64; d <<= 1) m = fmaxf(m, __shfl_xor(m, d, 64));
    float ex = act ? expf(o - m) : 0.f;
#pragma unroll
    for (int d = 1; d < 64; d <<= 1) ex += __shfl_xor(ex, d, 64);
    float ls = logf(ex) + m;
    if (act) out[(size_t)r * OUT_DIM + t] = o - ls;
}

// ================ fast BN stats for layer 2 (uint4 loads, LDS reduce, slice atomics) ================
__global__ __launch_bounds__(256) void k_bn_stats2(const ushort* __restrict__ H16,
                                                   float* __restrict__ bnacc) {
    __shared__ float ls[512];
    int t = threadIdx.x;
    ls[t] = 0.f; ls[t + 256] = 0.f;
    __syncthreads();
    int colb = (t & 31) * 8;
    float s[8], q[8];
#pragma unroll
    for (int j = 0; j < 8; j++) { s[j] = 0.f; q[j] = 0.f; }
    for (int rb = blockIdx.x * 8 + (t >> 5); rb < NN; rb += gridDim.x * 8) {
        uint4 v = *(const uint4*)(H16 + (size_t)rb * 256 + colb);
        float f[8] = { bflo(v.x), bfhi(v.x), bflo(v.y), bfhi(v.y),
                       bflo(v.z), bfhi(v.z), bflo(v.w), bfhi(v.w) };
#pragma unroll
        for (int j = 0; j < 8; j++) { s[j] += f[j]; q[j] += f[j] * f[j]; }
    }
#pragma unroll
    for (int j = 0; j < 8; j++) {
        atomicAdd(&ls[colb + j], s[j]);
        atomicAdd(&ls[256 + colb + j], q[j]);
    }
    __syncthreads();
    int slice = blockIdx.x & 7;
    atomicAdd(&bnacc[slice * 512 + t], ls[t]);
    atomicAdd(&bnacc[slice * 512 + 256 + t], ls[t + 256]);
}

// ================ launch ================

extern "C" void kernel_launch(void* const* d_in, const int* in_sizes, int n_in,
                              void* d_out, int out_size, void* d_ws, size_t ws_size,
                              hipStream_t stream) {
    const float* x     = (const float*)d_in[0];
    const int*   erow  = (const int*)d_in[1];
    const int*   ecol  = ((const int*)d_in[1]) + NE;
    const float* W1    = (const float*)d_in[2];
    const float* W2    = (const float*)d_in[4];
    const float* W3    = (const float*)d_in[6];
    const float* b3    = (const float*)d_in[7];
    const float* gamma = (const float*)d_in[8];
    const float* beta  = (const float*)d_in[9];
    float* out = (float*)d_out;

    char* ws = (char*)d_ws;
    size_t off = 0;
    auto alloc = [&](size_t bytes) -> void* {
        void* p = ws + off;
        off = (off + bytes + 255) & ~(size_t)255;
        return p;
    };
    float*    dinv     = (float*)alloc(NN * 4);
    unsigned* rowptr   = (unsigned*)alloc((NN + 1) * 4);
    int*      colidx   = (int*)alloc((size_t)NE * 4);
    float*    bnacc    = (float*)alloc(2 * 8 * 512 * 4);   // [0]=layer1, [1]=layer2
    unsigned* cnt      = (unsigned*)alloc((size_t)PB * NBK * 4);
    unsigned* boff     = (unsigned*)alloc((size_t)PB * NBK * 4);
    unsigned* bstart   = (unsigned*)alloc((NBK + 1) * 4);
    ushort*   Wt1      = (ushort*)alloc(128 * 256 * 2);
    ushort*   Wt2      = (ushort*)alloc(256 * 256 * 2);
    ushort*   Wt3      = (ushort*)alloc(48 * 256 * 2);
    uchar*    xs8      = (uchar*)alloc((size_t)NN * IN_DIM);       // fp8, sliced [4][NN][32]
    ushort*   Xa       = (ushort*)alloc((size_t)NN * IN_DIM * 2);  // aggregated x, bf16 row-major
    ushort*   H16      = (ushort*)alloc((size_t)NN * HID * 2);     // conv output, bf16
    uchar*    Ys2      = (uchar*)alloc((size_t)NN * HID);          // fp8, sliced [8][NN][32]
    ushort*   Ys3      = (ushort*)alloc((size_t)NN * 64 * 2);      // bf16 layer-3 transform

    float* bnacc1 = bnacc;
    float* bnacc2 = bnacc + 8 * 512;

    // aliases into H16 (25.6 MB), dead before gemm1 writes H16:
    unsigned* Pcol = (unsigned*)H16;                                   // 12.8 MB
    int2*     ebuf = (int2*)((char*)H16 + (size_t)13 * 1024 * 1024);   // 6.4 MB

    // --- preprocessing ---
    k_p1<<<HG + PB, 512, 0, stream>>>(erow, ecol, Pcol, cnt);
    k_p2<<<99, 256, 0, stream>>>(Pcol, dinv, cnt, boff, bstart);
    k_p3<<<PB + 6250 + 256, 256, 0, stream>>>(erow, ecol, boff, ebuf,
                                              x, dinv, xs8, W1, W2, W3, Wt1, Wt2, Wt3);
    k_part4<<<NBK, 256, 0, stream>>>(ebuf, bstart, rowptr, colidx);
    hipMemsetAsync(bnacc, 0, 2 * 8 * 512 * 4, stream);

    dim3 ggrid((NN + 63) / 64, 2);

    // --- layer 1: sliced gather (4 slices x 32 cols), transform + fused BN1 stats ---
    k_agg_sl<IN_DIM><<<dim3(4, 6250), 64, 0, stream>>>(xs8, rowptr, colidx, dinv, Xa);
    k_gemm1<IN_DIM><<<ggrid, 256, 0, stream>>>(Xa, Wt1, H16, bnacc1);

    // --- layer 2: BN1 prologue + fused staging; fp8 sliced output table ---
    k_gemm2<<<ggrid, 256, 0, stream>>>(H16, bnacc1, gamma, beta, Wt2, dinv, Ys2);
    k_agg_sl<HID><<<dim3(8, 6250), 64, 0, stream>>>(Ys2, rowptr, colidx, dinv, H16);
    k_bn_stats2<<<1024, 256, 0, stream>>>(H16, bnacc2);

    // --- layer 3: BN2 prologue in gemm3 ---
    k_gemm3<<<(NN + 63) / 64, 256, 0, stream>>>(H16, bnacc2, gamma, beta, Wt3, dinv, Ys3);
    k_agg_lsm<<<NN, 64, 0, stream>>>(Ys3, rowptr, colidx, dinv, b3, out);
}

// Round 10
// 315.031 us; speedup vs baseline: 1.3659x; 1.3659x over previous
//
#include <hip/hip_runtime.h>
#include <math.h>

#define NN 50000
#define NE 800000
#define IN_DIM 128
#define HID 256
#define OUT_DIM 40
#define BN_EPS 1e-5f

#define HG 128          // histogram blocks (col-degree)
#define HW 25000        // packed words (2 nodes/word)
#define HPASS 12800     // words per LDS pass

#define NBK 196         // row buckets (256 rows each)
#define PB 256          // partition blocks
#define EPB (NE / PB)   // 3125 edges per partition block

typedef __attribute__((ext_vector_type(8))) short short8;
typedef __attribute__((ext_vector_type(4))) float f32x4;
typedef __attribute__((ext_vector_type(2))) float f32x2;

__device__ __forceinline__ ushort f2bf(float f) {
    union { float f; unsigned u; } v; v.f = f;
    unsigned r = v.u + 0x7fffu + ((v.u >> 16) & 1u);
    return (ushort)(r >> 16);
}
__device__ __forceinline__ float bflo(unsigned u) {
    union { unsigned a; float f; } v; v.a = u << 16; return v.f;
}
__device__ __forceinline__ float bfhi(unsigned u) {
    union { unsigned a; float f; } v; v.a = u & 0xffff0000u; return v.f;
}
// fp8 e4m3 (OCP) via HW converts — word-select must be a literal constant
__device__ __forceinline__ f32x2 fp8_dec_lo(int v) {
    return __builtin_amdgcn_cvt_pk_f32_fp8(v, false);
}
__device__ __forceinline__ f32x2 fp8_dec_hi(int v) {
    return __builtin_amdgcn_cvt_pk_f32_fp8(v, true);
}
__device__ __forceinline__ int fp8_enc_lo(float a, float b, int old) {
    return __builtin_amdgcn_cvt_pk_fp8_f32(a, b, old, false);
}
__device__ __forceinline__ int fp8_enc_hi(float a, float b, int old) {
    return __builtin_amdgcn_cvt_pk_fp8_f32(a, b, old, true);
}

// ================ P1: col-degree LDS histogram (blocks 0..HG) + row-bucket counts (HG..HG+PB) ================
__global__ __launch_bounds__(512) void k_p1(const int* __restrict__ erow,
                                            const int* __restrict__ ecol,
                                            unsigned* __restrict__ Pcol,
                                            unsigned* __restrict__ cnt) {
    __shared__ unsigned lds[HPASS];
    int t = threadIdx.x;
    int b = blockIdx.x;
    if (b < HG) {
        unsigned* partial = Pcol + (size_t)b * HW;
        int e0 = b * (NE / HG), e1 = e0 + (NE / HG);
#pragma unroll
        for (int pass = 0; pass < 2; pass++) {
            int wbase = pass ? HPASS : 0;
            int wend = pass ? HW : HPASS;
            int nw = wend - wbase;
            for (int w = t; w < HPASS; w += 512) lds[w] = 0u;
            __syncthreads();
            int vlo = wbase * 2, vhi = wend * 2;
            for (int e = e0 + t; e < e1; e += 512) {
                int v = ecol[e];
                if (v >= vlo && v < vhi)
                    atomicAdd(&lds[(v >> 1) - wbase], (v & 1) ? 0x10000u : 1u);
            }
            __syncthreads();
            for (int w = t; w < nw; w += 512) partial[wbase + w] = lds[w];
            __syncthreads();
        }
    } else {
        int bb = b - HG;
        for (int i = t; i < NBK; i += 512) lds[i] = 0u;
        __syncthreads();
        int e0 = bb * EPB;
        for (int i = t; i < EPB; i += 512) atomicAdd(&lds[((unsigned)erow[e0 + i]) >> 8], 1u);
        __syncthreads();
        for (int i = t; i < NBK; i += 512) cnt[bb * NBK + i] = lds[i];
    }
}

// ================ P2: hist reduce -> dinv (blocks 0..97) + bucket scan/offsets (block 98) ================
__global__ __launch_bounds__(256) void k_p2(const unsigned* __restrict__ Pcol,
                                            float* __restrict__ dinv,
                                            const unsigned* __restrict__ cnt,
                                            unsigned* __restrict__ off,
                                            unsigned* __restrict__ bstart) {
    int t = threadIdx.x;
    if (blockIdx.x < 98) {
        int w = blockIdx.x * 256 + t;
        if (w >= HW) return;
        unsigned sc = 0;
        for (int b = 0; b < HG; b++) sc += Pcol[(size_t)b * HW + w];
        dinv[2 * w] = rsqrtf((float)((sc & 0xffffu) + 1u));
        dinv[2 * w + 1] = rsqrtf((float)((sc >> 16) + 1u));
    } else {
        __shared__ unsigned s[256];
        unsigned tot = 0;
        if (t < NBK) for (int b = 0; b < PB; b++) tot += cnt[b * NBK + t];
        s[t] = tot;
        __syncthreads();
        for (int o = 1; o < 256; o <<= 1) {
            unsigned x = (t >= o) ? s[t - o] : 0u;
            __syncthreads();
            s[t] += x;
            __syncthreads();
        }
        unsigned base = s[t] - tot;
        if (t < NBK) bstart[t] = base;
        if (t == NBK - 1) bstart[NBK] = base + tot;
        if (t < NBK) {
            unsigned run = base;
            for (int b = 0; b < PB; b++) { off[b * NBK + t] = run; run += cnt[b * NBK + t]; }
        }
    }
}

// ================ P3: edge scatter into buckets (blocks 0..PB) + input prep (rest) ================
__global__ __launch_bounds__(256) void k_p3(const int* __restrict__ erow,
                                            const int* __restrict__ ecol,
                                            const unsigned* __restrict__ off,
                                            int2* __restrict__ ebuf,
                                            const float* __restrict__ x,
                                            const float* __restrict__ dinv,
                                            uchar* __restrict__ xs8,
                                            const float* __restrict__ W1,
                                            const float* __restrict__ W2,
                                            const float* __restrict__ W3,
                                            ushort* __restrict__ Wt1,
                                            ushort* __restrict__ Wt2,
                                            ushort* __restrict__ Wt3) {
    int t = threadIdx.x, b = blockIdx.x;
    if (b < PB) {
        __shared__ unsigned c[NBK];
        for (int i = t; i < NBK; i += 256) c[i] = off[b * NBK + i];
        __syncthreads();
        int e0 = b * EPB;
        for (int i = t; i < EPB; i += 256) {
            int r = erow[e0 + i], cc = ecol[e0 + i];
            unsigned p = atomicAdd(&c[((unsigned)r) >> 8], 1u);
            ebuf[p] = make_int2(r, cc);
        }
    } else if (b < PB + 6250) {
        int i = (b - PB) * 256 + t;   // over N*128/4 = 1.6M exactly
        int row = i >> 5;
        float d = dinv[row];
        float4 v = ((const float4*)x)[i];
        int p = fp8_enc_lo(v.x * d, v.y * d, 0);
        p = fp8_enc_hi(v.z * d, v.w * d, p);
        ((int*)xs8)[i] = p;
    } else {
        int i = (b - PB - 6250) * 256 + t;
        if (i < 128 * 256) { int k = i / 256, n = i % 256; Wt1[n * 128 + k] = f2bf(W1[i]); }
        if (i < 256 * 256) { int k = i / 256, n = i % 256; Wt2[n * 256 + k] = f2bf(W2[i]); }
        if (i < 48 * 256)  { int n = i / 256, k = i % 256;
                             Wt3[i] = (n < OUT_DIM) ? f2bf(W3[k * OUT_DIM + n]) : (ushort)0; }
    }
}

// ================ P4: per-bucket row counts -> rowptr -> colidx fill ================
__global__ __launch_bounds__(256) void k_part4(const int2* __restrict__ ebuf,
                                               const unsigned* __restrict__ bstart,
                                               unsigned* __restrict__ rowptr,
                                               int* __restrict__ colidx) {
    __shared__ unsigned rc[256], cur[256], s[256];
    int t = threadIdx.x, b = blockIdx.x;
    unsigned ebase = bstart[b], ecnt = bstart[b + 1] - ebase;
    rc[t] = 0u;
    __syncthreads();
    for (unsigned i = t; i < ecnt; i += 256) atomicAdd(&rc[ebuf[ebase + i].x & 255], 1u);
    __syncthreads();
    unsigned v = rc[t];
    s[t] = v;
    __syncthreads();
    for (int o = 1; o < 256; o <<= 1) {
        unsigned x = (t >= o) ? s[t - o] : 0u;
        __syncthreads();
        s[t] += x;
        __syncthreads();
    }
    unsigned excl = s[t] - v;
    int row = (b << 8) + t;
    if (row < NN) rowptr[row] = ebase + excl;
    cur[t] = ebase + excl;
    if (b == 0 && t == 0) rowptr[NN] = NE;
    __syncthreads();
    for (unsigned i = t; i < ecnt; i += 256) {
        int2 e = ebuf[ebase + i];
        unsigned p = atomicAdd(&cur[e.x & 255], 1u);
        colidx[p] = e.y;
    }
}

// ================ layer-1 aggregation on fp8 features (128-dim row-major, unroll-8) ================
__global__ __launch_bounds__(64) void k_agg_x(const uchar* __restrict__ xs8,
                                              const unsigned* __restrict__ rowptr,
                                              const int* __restrict__ colidx,
                                              const float* __restrict__ dinv,
                                              ushort* __restrict__ Xa) {
    int r = blockIdx.x;
    int t = threadIdx.x;  // 64 lanes x 2 fp8 cols
    const ushort* Xv = (const ushort*)xs8;
    f32x2 sf = fp8_dec_lo((int)Xv[(size_t)r * 64 + t]);
    float a0 = sf[0], a1 = sf[1];
    unsigned e0 = rowptr[r], e1 = rowptr[r + 1];
    unsigned e = e0;
    for (; e + 8 <= e1; e += 8) {
        int v0 = Xv[(size_t)colidx[e] * 64 + t];
        int v1 = Xv[(size_t)colidx[e + 1] * 64 + t];
        int v2 = Xv[(size_t)colidx[e + 2] * 64 + t];
        int v3 = Xv[(size_t)colidx[e + 3] * 64 + t];
        int v4 = Xv[(size_t)colidx[e + 4] * 64 + t];
        int v5 = Xv[(size_t)colidx[e + 5] * 64 + t];
        int v6 = Xv[(size_t)colidx[e + 6] * 64 + t];
        int v7 = Xv[(size_t)colidx[e + 7] * 64 + t];
        f32x2 f0 = fp8_dec_lo(v0), f1 = fp8_dec_lo(v1);
        f32x2 f2 = fp8_dec_lo(v2), f3 = fp8_dec_lo(v3);
        f32x2 f4 = fp8_dec_lo(v4), f5 = fp8_dec_lo(v5);
        f32x2 f6 = fp8_dec_lo(v6), f7 = fp8_dec_lo(v7);
        a0 += f0[0] + f1[0] + f2[0] + f3[0] + f4[0] + f5[0] + f6[0] + f7[0];
        a1 += f0[1] + f1[1] + f2[1] + f3[1] + f4[1] + f5[1] + f6[1] + f7[1];
    }
    for (; e < e1; e++) {
        f32x2 f = fp8_dec_lo((int)Xv[(size_t)colidx[e] * 64 + t]);
        a0 += f[0]; a1 += f[1];
    }
    float dr = dinv[r];
    ((unsigned*)Xa)[(size_t)r * 64 + t] = (unsigned)f2bf(dr * a0) | ((unsigned)f2bf(dr * a1) << 16);
}

// ================ MFMA GEMM 1 (+fused BN1 column stats): H16 = Xa @ Wt1^T ================
template <int K>
__global__ __launch_bounds__(256) void k_gemm1(const ushort* __restrict__ A,
                                               const ushort* __restrict__ Bt,
                                               ushort* __restrict__ H16,
                                               float* __restrict__ bnacc) {
    constexpr int BK = 32;
    constexpr int LD = 40;
    __shared__ ushort sA[64 * LD];
    __shared__ ushort sB[128 * LD];
    int t = threadIdx.x;
    int wave = t >> 6, lane = t & 63;
    int quad = lane >> 4, m15 = lane & 15;
    long r0 = (long)blockIdx.x * 64;
    int n0 = blockIdx.y * 128;

    f32x4 acc[8];
#pragma unroll
    for (int i = 0; i < 8; i++) { acc[i][0] = 0.f; acc[i][1] = 0.f; acc[i][2] = 0.f; acc[i][3] = 0.f; }

    for (int k0 = 0; k0 < K; k0 += BK) {
        {
            int row = t >> 2, seg = (t & 3) * 8;
            long gr = r0 + row;
            uint4 v = make_uint4(0, 0, 0, 0);
            if (gr < NN) v = *(const uint4*)(A + gr * K + k0 + seg);
            *(uint4*)(sA + row * LD + seg) = v;
        }
        {
            int n = t >> 1, seg = (t & 1) * 16;
            const uint4* src = (const uint4*)(Bt + (long)(n0 + n) * K + k0 + seg);
            uint4 b0 = src[0], b1 = src[1];
            *(uint4*)(sB + n * LD + seg) = b0;
            *(uint4*)(sB + n * LD + seg + 8) = b1;
        }
        __syncthreads();
        short8 a = *(const short8*)(sA + (wave * 16 + m15) * LD + quad * 8);
#pragma unroll
        for (int ct = 0; ct < 8; ct++) {
            short8 b = *(const short8*)(sB + (ct * 16 + m15) * LD + quad * 8);
            acc[ct] = __builtin_amdgcn_mfma_f32_16x16x32_bf16(a, b, acc[ct], 0, 0, 0);
        }
        __syncthreads();
    }
    long rowbase = r0 + wave * 16 + quad * 4;
#pragma unroll
    for (int ct = 0; ct < 8; ct++) {
        int col = n0 + ct * 16 + m15;
#pragma unroll
        for (int rg = 0; rg < 4; rg++) {
            long gr = rowbase + rg;
            if (gr < NN) H16[gr * 256 + col] = f2bf(acc[ct][rg]);
        }
    }
    // ---- fused BN1 column stats (guard rows are exact zeros) ----
    float* ldsS = (float*)(void*)sA;
    float* ldsQ = (float*)(void*)sB;
#pragma unroll
    for (int ct = 0; ct < 8; ct++) {
        float s = acc[ct][0] + acc[ct][1] + acc[ct][2] + acc[ct][3];
        float q = acc[ct][0] * acc[ct][0] + acc[ct][1] * acc[ct][1]
                + acc[ct][2] * acc[ct][2] + acc[ct][3] * acc[ct][3];
        s += __shfl_xor(s, 16, 64); q += __shfl_xor(q, 16, 64);
        s += __shfl_xor(s, 32, 64); q += __shfl_xor(q, 32, 64);
        if (quad == 0) {
            ldsS[wave * 128 + ct * 16 + m15] = s;
            ldsQ[wave * 128 + ct * 16 + m15] = q;
        }
    }
    __syncthreads();
    {
        int c = t & 127;
        int slice = blockIdx.x & 7;
        float v = (t < 128)
            ? ldsS[c] + ldsS[128 + c] + ldsS[256 + c] + ldsS[384 + c]
            : ldsQ[c] + ldsQ[128 + c] + ldsQ[256 + c] + ldsQ[384 + c];
        atomicAdd(&bnacc[slice * 512 + ((t < 128) ? 0 : 256) + n0 + c], v);
    }
}

// BN scale/shift prologue: reduce 8 slices of bnacc into LDS (256 threads)
__device__ __forceinline__ void bn_prolog(const float* __restrict__ bnacc,
                                          const float* __restrict__ gamma,
                                          const float* __restrict__ beta,
                                          float* __restrict__ bnsc,
                                          float* __restrict__ bnsh, int t) {
    float s = 0.f, q = 0.f;
#pragma unroll
    for (int sl = 0; sl < 8; sl++) {
        s += bnacc[sl * 512 + t];
        q += bnacc[sl * 512 + 256 + t];
    }
    float mu = s * (1.f / NN);
    float var = q * (1.f / NN) - mu * mu;
    float g = gamma[t] * rsqrtf(var + BN_EPS);
    bnsc[t] = g;
    bnsh[t] = beta[t] - mu * g;
}

// BN+ReLU stage of 8 bf16 cols from H16 row into LDS (scale/shift from LDS)
__device__ __forceinline__ void bn_stage8(const ushort* __restrict__ Hrow, bool valid,
                                          const float* __restrict__ bnsc,
                                          const float* __restrict__ bnsh, int col0,
                                          ushort* __restrict__ dst) {
    uint4 hv = make_uint4(0, 0, 0, 0);
    if (valid) hv = *(const uint4*)(Hrow + col0);
    float f[8] = { bflo(hv.x), bfhi(hv.x), bflo(hv.y), bfhi(hv.y),
                   bflo(hv.z), bfhi(hv.z), bflo(hv.w), bfhi(hv.w) };
#pragma unroll
    for (int j = 0; j < 8; j++)
        dst[j] = f2bf(fmaxf(f[j] * bnsc[col0 + j] + bnsh[col0 + j], 0.f));
}

// ================ MFMA GEMM 2: Ys2(fp8, row-major) = fp8( dinv * (relu(bn(H16)) @ Wt2^T) ) ================
__global__ __launch_bounds__(256) void k_gemm2(const ushort* __restrict__ H16,
                                               const float* __restrict__ bnacc,
                                               const float* __restrict__ gamma,
                                               const float* __restrict__ beta,
                                               const ushort* __restrict__ Bt,
                                               const float* __restrict__ dinv,
                                               uchar* __restrict__ Y8) {
    constexpr int K = 256, BK = 32, LD = 40;
    __shared__ ushort sA[64 * LD];
    __shared__ ushort sB[128 * LD];
    __shared__ float bnsc[256], bnsh[256];
    int t = threadIdx.x;
    int wave = t >> 6, lane = t & 63;
    int quad = lane >> 4, m15 = lane & 15;
    long r0 = (long)blockIdx.x * 64;
    int n0 = blockIdx.y * 128;

    bn_prolog(bnacc, gamma, beta, bnsc, bnsh, t);
    __syncthreads();

    f32x4 acc[8];
#pragma unroll
    for (int i = 0; i < 8; i++) { acc[i][0] = 0.f; acc[i][1] = 0.f; acc[i][2] = 0.f; acc[i][3] = 0.f; }

    for (int k0 = 0; k0 < K; k0 += BK) {
        {
            int row = t >> 2, seg = (t & 3) * 8;
            long gr = r0 + row;
            bn_stage8(H16 + gr * 256, gr < NN, bnsc, bnsh, k0 + seg, sA + row * LD + seg);
        }
        {
            int n = t >> 1, seg = (t & 1) * 16;
            const uint4* src = (const uint4*)(Bt + (long)(n0 + n) * K + k0 + seg);
            uint4 b0 = src[0], b1 = src[1];
            *(uint4*)(sB + n * LD + seg) = b0;
            *(uint4*)(sB + n * LD + seg + 8) = b1;
        }
        __syncthreads();
        short8 a = *(const short8*)(sA + (wave * 16 + m15) * LD + quad * 8);
#pragma unroll
        for (int ct = 0; ct < 8; ct++) {
            short8 b = *(const short8*)(sB + (ct * 16 + m15) * LD + quad * 8);
            acc[ct] = __builtin_amdgcn_mfma_f32_16x16x32_bf16(a, b, acc[ct], 0, 0, 0);
        }
        __syncthreads();
    }
    long rowbase = r0 + wave * 16 + quad * 4;
    float dv[4];
#pragma unroll
    for (int rg = 0; rg < 4; rg++) dv[rg] = (rowbase + rg < NN) ? dinv[rowbase + rg] : 0.f;
#pragma unroll
    for (int ct = 0; ct < 8; ct++) {
        int col = n0 + ct * 16 + m15;
#pragma unroll
        for (int rg = 0; rg < 4; rg++) {
            long gr = rowbase + rg;
            if (gr < NN) {
                int p = fp8_enc_lo(dv[rg] * acc[ct][rg], 0.f, 0);
                Y8[gr * 256 + col] = (uchar)(p & 0xff);
            }
        }
    }
}

// ================ MFMA GEMM 3: Ys3 (stride 64, bf16) = dinv * (relu(bn2(H16)) @ Wt3^T) ================
__global__ __launch_bounds__(256) void k_gemm3(const ushort* __restrict__ H16,
                                               const float* __restrict__ bnacc,
                                               const float* __restrict__ gamma,
                                               const float* __restrict__ beta,
                                               const ushort* __restrict__ Wt3,
                                               const float* __restrict__ dinv,
                                               ushort* __restrict__ Y) {
    constexpr int LD = 264;
    __shared__ ushort sA[64 * LD];
    __shared__ ushort sB[48 * LD];
    __shared__ float bnsc[256], bnsh[256];
    int t = threadIdx.x;
    int wave = t >> 6, lane = t & 63;
    int quad = lane >> 4, m15 = lane & 15;
    long r0 = (long)blockIdx.x * 64;

    bn_prolog(bnacc, gamma, beta, bnsc, bnsh, t);
    __syncthreads();

    for (int idx = t; idx < 48 * 16; idx += 256) {
        int n = idx >> 4, s = (idx & 15) * 16;
        const uint4* src = (const uint4*)(Wt3 + n * 256 + s);
        *(uint4*)(sB + n * LD + s) = src[0];
        *(uint4*)(sB + n * LD + s + 8) = src[1];
    }
    {
        int row = t >> 2;
        long gr = r0 + row;
#pragma unroll
        for (int s8 = 0; s8 < 8; s8++) {
            int seg = s8 * 32 + (t & 3) * 8;
            bn_stage8(H16 + gr * 256, gr < NN, bnsc, bnsh, seg, sA + row * LD + seg);
        }
    }
    __syncthreads();

    f32x4 acc[3];
#pragma unroll
    for (int i = 0; i < 3; i++) { acc[i][0] = 0.f; acc[i][1] = 0.f; acc[i][2] = 0.f; acc[i][3] = 0.f; }
#pragma unroll
    for (int k0 = 0; k0 < 256; k0 += 32) {
        short8 a = *(const short8*)(sA + (wave * 16 + m15) * LD + k0 + quad * 8);
#pragma unroll
        for (int ct = 0; ct < 3; ct++) {
            short8 b = *(const short8*)(sB + (ct * 16 + m15) * LD + k0 + quad * 8);
            acc[ct] = __builtin_amdgcn_mfma_f32_16x16x32_bf16(a, b, acc[ct], 0, 0, 0);
        }
    }
    long rowbase = r0 + wave * 16 + quad * 4;
#pragma unroll
    for (int ct = 0; ct < 3; ct++) {
        int col = ct * 16 + m15;
#pragma unroll
        for (int rg = 0; rg < 4; rg++) {
            long gr = rowbase + rg;
            if (gr < NN) Y[gr * 64 + col] = f2bf(dinv[gr] * acc[ct][rg]);
        }
    }
}

// ================ layer-2 aggregation: fp8 row-major gather -> bf16 H16 (unroll-8) ================
__global__ __launch_bounds__(64) void k_agg_hid(const uchar* __restrict__ Y8,
                                                const unsigned* __restrict__ rowptr,
                                                const int* __restrict__ colidx,
                                                const float* __restrict__ dinv,
                                                ushort* __restrict__ H16) {
    int r = blockIdx.x;
    int t = threadIdx.x;  // 64 lanes x 4 fp8 cols
    const int* Yv = (const int*)Y8;
    int y = Yv[(size_t)r * 64 + t];
    f32x2 yl = fp8_dec_lo(y), yh = fp8_dec_hi(y);
    float a0 = yl[0], a1 = yl[1], a2 = yh[0], a3 = yh[1];
    unsigned e0 = rowptr[r], e1 = rowptr[r + 1];
    unsigned e = e0;
    for (; e + 8 <= e1; e += 8) {
        int v0 = Yv[(size_t)colidx[e] * 64 + t];
        int v1 = Yv[(size_t)colidx[e + 1] * 64 + t];
        int v2 = Yv[(size_t)colidx[e + 2] * 64 + t];
        int v3 = Yv[(size_t)colidx[e + 3] * 64 + t];
        int v4 = Yv[(size_t)colidx[e + 4] * 64 + t];
        int v5 = Yv[(size_t)colidx[e + 5] * 64 + t];
        int v6 = Yv[(size_t)colidx[e + 6] * 64 + t];
        int v7 = Yv[(size_t)colidx[e + 7] * 64 + t];
        f32x2 l0 = fp8_dec_lo(v0), h0 = fp8_dec_hi(v0);
        f32x2 l1 = fp8_dec_lo(v1), h1 = fp8_dec_hi(v1);
        f32x2 l2 = fp8_dec_lo(v2), h2 = fp8_dec_hi(v2);
        f32x2 l3 = fp8_dec_lo(v3), h3 = fp8_dec_hi(v3);
        f32x2 l4 = fp8_dec_lo(v4), h4 = fp8_dec_hi(v4);
        f32x2 l5 = fp8_dec_lo(v5), h5 = fp8_dec_hi(v5);
        f32x2 l6 = fp8_dec_lo(v6), h6 = fp8_dec_hi(v6);
        f32x2 l7 = fp8_dec_lo(v7), h7 = fp8_dec_hi(v7);
        a0 += l0[0] + l1[0] + l2[0] + l3[0] + l4[0] + l5[0] + l6[0] + l7[0];
        a1 += l0[1] + l1[1] + l2[1] + l3[1] + l4[1] + l5[1] + l6[1] + l7[1];
        a2 += h0[0] + h1[0] + h2[0] + h3[0] + h4[0] + h5[0] + h6[0] + h7[0];
        a3 += h0[1] + h1[1] + h2[1] + h3[1] + h4[1] + h5[1] + h6[1] + h7[1];
    }
    for (; e < e1; e++) {
        int v = Yv[(size_t)colidx[e] * 64 + t];
        f32x2 l = fp8_dec_lo(v), h = fp8_dec_hi(v);
        a0 += l[0]; a1 += l[1]; a2 += h[0]; a3 += h[1];
    }
    float dr = dinv[r];
    uint2 o;
    o.x = (unsigned)f2bf(dr * a0) | ((unsigned)f2bf(dr * a1) << 16);
    o.y = (unsigned)f2bf(dr * a2) | ((unsigned)f2bf(dr * a3) << 16);
    ((uint2*)H16)[(size_t)r * 64 + t] = o;
}

// ================ layer-3 aggregation + bias + log_softmax ================
__global__ __launch_bounds__(64) void k_agg_lsm(const ushort* __restrict__ Y,
                                                const unsigned* __restrict__ rowptr,
                                                const int* __restrict__ colidx,
                                                const float* __restrict__ dinv,
                                                const float* __restrict__ b3,
                                                float* __restrict__ out) {
    int r = blockIdx.x;
    int t = threadIdx.x;
    bool act = t < OUT_DIM;
    float acc = act ? bflo((unsigned)Y[(size_t)r * 64 + t]) : 0.f;
    unsigned e0 = rowptr[r], e1 = rowptr[r + 1];
    unsigned e = e0;
    for (; e + 4 <= e1; e += 4) {
        int c0 = colidx[e], c1 = colidx[e + 1], c2 = colidx[e + 2], c3 = colidx[e + 3];
        if (act) {
            acc += bflo((unsigned)Y[(size_t)c0 * 64 + t]) + bflo((unsigned)Y[(size_t)c1 * 64 + t])
                 + bflo((unsigned)Y[(size_t)c2 * 64 + t]) + bflo((unsigned)Y[(size_t)c3 * 64 + t]);
        }
    }
    for (; e < e1; e++) {
        if (act) acc += bflo((unsigned)Y[(size_t)colidx[e] * 64 + t]);
    }
    float o = act ? (dinv[r] * acc + b3[t]) : 0.f;
    float m = act ? o : -1e30f;
#pragma unroll
    for (int d = 1; d < 64; d <<= 1) m = fmaxf(m, __shfl_xor(m, d, 64));
    float ex = act ? expf(o - m) : 0.f;
#pragma unroll
    for (int d = 1; d < 64; d <<= 1) ex += __shfl_xor(ex, d, 64);
    float ls = logf(ex) + m;
    if (act) out[(size_t)r * OUT_DIM + t] = o - ls;
}

// ================ fast BN stats for layer 2 (uint4 loads, LDS reduce, slice atomics) ================
__global__ __launch_bounds__(256) void k_bn_stats2(const ushort* __restrict__ H16,
                                                   float* __restrict__ bnacc) {
    __shared__ float ls[512];
    int t = threadIdx.x;
    ls[t] = 0.f; ls[t + 256] = 0.f;
    __syncthreads();
    int colb = (t & 31) * 8;
    float s[8], q[8];
#pragma unroll
    for (int j = 0; j < 8; j++) { s[j] = 0.f; q[j] = 0.f; }
    for (int rb = blockIdx.x * 8 + (t >> 5); rb < NN; rb += gridDim.x * 8) {
        uint4 v = *(const uint4*)(H16 + (size_t)rb * 256 + colb);
        float f[8] = { bflo(v.x), bfhi(v.x), bflo(v.y), bfhi(v.y),
                       bflo(v.z), bfhi(v.z), bflo(v.w), bfhi(v.w) };
#pragma unroll
        for (int j = 0; j < 8; j++) { s[j] += f[j]; q[j] += f[j] * f[j]; }
    }
#pragma unroll
    for (int j = 0; j < 8; j++) {
        atomicAdd(&ls[colb + j], s[j]);
        atomicAdd(&ls[256 + colb + j], q[j]);
    }
    __syncthreads();
    int slice = blockIdx.x & 7;
    atomicAdd(&bnacc[slice * 512 + t], ls[t]);
    atomicAdd(&bnacc[slice * 512 + 256 + t], ls[t + 256]);
}

// ================ launch ================

extern "C" void kernel_launch(void* const* d_in, const int* in_sizes, int n_in,
                              void* d_out, int out_size, void* d_ws, size_t ws_size,
                              hipStream_t stream) {
    const float* x     = (const float*)d_in[0];
    const int*   erow  = (const int*)d_in[1];
    const int*   ecol  = ((const int*)d_in[1]) + NE;
    const float* W1    = (const float*)d_in[2];
    const float* W2    = (const float*)d_in[4];
    const float* W3    = (const float*)d_in[6];
    const float* b3    = (const float*)d_in[7];
    const float* gamma = (const float*)d_in[8];
    const float* beta  = (const float*)d_in[9];
    float* out = (float*)d_out;

    char* ws = (char*)d_ws;
    size_t off = 0;
    auto alloc = [&](size_t bytes) -> void* {
        void* p = ws + off;
        off = (off + bytes + 255) & ~(size_t)255;
        return p;
    };
    float*    dinv     = (float*)alloc(NN * 4);
    unsigned* rowptr   = (unsigned*)alloc((NN + 1) * 4);
    int*      colidx   = (int*)alloc((size_t)NE * 4);
    float*    bnacc    = (float*)alloc(2 * 8 * 512 * 4);   // [0]=layer1, [1]=layer2
    unsigned* cnt      = (unsigned*)alloc((size_t)PB * NBK * 4);
    unsigned* boff     = (unsigned*)alloc((size_t)PB * NBK * 4);
    unsigned* bstart   = (unsigned*)alloc((NBK + 1) * 4);
    ushort*   Wt1      = (ushort*)alloc(128 * 256 * 2);
    ushort*   Wt2      = (ushort*)alloc(256 * 256 * 2);
    ushort*   Wt3      = (ushort*)alloc(48 * 256 * 2);
    uchar*    xs8      = (uchar*)alloc((size_t)NN * IN_DIM);       // fp8 dinv-scaled x, row-major
    ushort*   Xa       = (ushort*)alloc((size_t)NN * IN_DIM * 2);  // aggregated x, bf16
    ushort*   H16      = (ushort*)alloc((size_t)NN * HID * 2);     // conv output, bf16
    uchar*    Ys2      = (uchar*)alloc((size_t)NN * HID);          // fp8 layer-2 transform, row-major
    ushort*   Ys3      = (ushort*)alloc((size_t)NN * 64 * 2);      // bf16 layer-3 transform

    float* bnacc1 = bnacc;
    float* bnacc2 = bnacc + 8 * 512;

    // aliases into H16 (25.6 MB), dead before gemm1 writes H16:
    unsigned* Pcol = (unsigned*)H16;                                   // 12.8 MB
    int2*     ebuf = (int2*)((char*)H16 + (size_t)13 * 1024 * 1024);   // 6.4 MB

    // --- preprocessing ---
    k_p1<<<HG + PB, 512, 0, stream>>>(erow, ecol, Pcol, cnt);
    k_p2<<<99, 256, 0, stream>>>(Pcol, dinv, cnt, boff, bstart);
    k_p3<<<PB + 6250 + 256, 256, 0, stream>>>(erow, ecol, boff, ebuf,
                                              x, dinv, xs8, W1, W2, W3, Wt1, Wt2, Wt3);
    k_part4<<<NBK, 256, 0, stream>>>(ebuf, bstart, rowptr, colidx);
    hipMemsetAsync(bnacc, 0, 2 * 8 * 512 * 4, stream);

    dim3 ggrid((NN + 63) / 64, 2);

    // --- layer 1: fp8 gather, transform + fused BN1 stats ---
    k_agg_x<<<NN, 64, 0, stream>>>(xs8, rowptr, colidx, dinv, Xa);
    k_gemm1<IN_DIM><<<ggrid, 256, 0, stream>>>(Xa, Wt1, H16, bnacc1);

    // --- layer 2: BN1 prologue + fused staging; fp8 row-major output table ---
    k_gemm2<<<ggrid, 256, 0, stream>>>(H16, bnacc1, gamma, beta, Wt2, dinv, Ys2);
    k_agg_hid<<<NN, 64, 0, stream>>>(Ys2, rowptr, colidx, dinv, H16);
    k_bn_stats2<<<1024, 256, 0, stream>>>(H16, bnacc2);

    // --- layer 3: BN2 prologue in gemm3 ---
    k_gemm3<<<(NN + 63) / 64, 256, 0, stream>>>(H16, bnacc2, gamma, beta, Wt3, dinv, Ys3);
    k_agg_lsm<<<NN, 64, 0, stream>>>(Ys3, rowptr, colidx, dinv, b3, out);
}

// Round 11
// 313.139 us; speedup vs baseline: 1.3741x; 1.0060x over previous
//
#include <hip/hip_runtime.h>
#include <math.h>

#define NN 50000
#define NE 800000
#define IN_DIM 128
#define HID 256
#define OUT_DIM 40
#define BN_EPS 1e-5f

#define HG 128          // histogram blocks (col-degree)
#define HW 25000        // packed words (2 nodes/word)
#define HPASS 12800     // words per LDS pass

#define NBK 196         // row buckets (256 rows each)
#define PB 256          // partition blocks
#define EPB (NE / PB)   // 3125 edges per partition block

typedef __attribute__((ext_vector_type(8))) short short8;
typedef __attribute__((ext_vector_type(4))) float f32x4;
typedef __attribute__((ext_vector_type(2))) float f32x2;

__device__ __forceinline__ ushort f2bf(float f) {
    union { float f; unsigned u; } v; v.f = f;
    unsigned r = v.u + 0x7fffu + ((v.u >> 16) & 1u);
    return (ushort)(r >> 16);
}
__device__ __forceinline__ unsigned pack2bf(float a, float b) {
    return (unsigned)f2bf(a) | ((unsigned)f2bf(b) << 16);
}
__device__ __forceinline__ float bflo(unsigned u) {
    union { unsigned a; float f; } v; v.a = u << 16; return v.f;
}
__device__ __forceinline__ float bfhi(unsigned u) {
    union { unsigned a; float f; } v; v.a = u & 0xffff0000u; return v.f;
}
// fp8 e4m3 (OCP) via HW converts — word-select must be a literal constant
__device__ __forceinline__ f32x2 fp8_dec_lo(int v) {
    return __builtin_amdgcn_cvt_pk_f32_fp8(v, false);
}
__device__ __forceinline__ f32x2 fp8_dec_hi(int v) {
    return __builtin_amdgcn_cvt_pk_f32_fp8(v, true);
}
__device__ __forceinline__ int fp8_enc_lo(float a, float b, int old) {
    return __builtin_amdgcn_cvt_pk_fp8_f32(a, b, old, false);
}
__device__ __forceinline__ int fp8_enc_hi(float a, float b, int old) {
    return __builtin_amdgcn_cvt_pk_fp8_f32(a, b, old, true);
}

// ================ P1: col-degree LDS histogram (blocks 0..HG) + row-bucket counts (HG..HG+PB) ================
__global__ __launch_bounds__(512) void k_p1(const int* __restrict__ erow,
                                            const int* __restrict__ ecol,
                                            unsigned* __restrict__ Pcol,
                                            unsigned* __restrict__ cnt) {
    __shared__ unsigned lds[HPASS];
    int t = threadIdx.x;
    int b = blockIdx.x;
    if (b < HG) {
        unsigned* partial = Pcol + (size_t)b * HW;
        int e0 = b * (NE / HG), e1 = e0 + (NE / HG);
#pragma unroll
        for (int pass = 0; pass < 2; pass++) {
            int wbase = pass ? HPASS : 0;
            int wend = pass ? HW : HPASS;
            int nw = wend - wbase;
            for (int w = t; w < HPASS; w += 512) lds[w] = 0u;
            __syncthreads();
            int vlo = wbase * 2, vhi = wend * 2;
            for (int e = e0 + t; e < e1; e += 512) {
                int v = ecol[e];
                if (v >= vlo && v < vhi)
                    atomicAdd(&lds[(v >> 1) - wbase], (v & 1) ? 0x10000u : 1u);
            }
            __syncthreads();
            for (int w = t; w < nw; w += 512) partial[wbase + w] = lds[w];
            __syncthreads();
        }
    } else {
        int bb = b - HG;
        for (int i = t; i < NBK; i += 512) lds[i] = 0u;
        __syncthreads();
        int e0 = bb * EPB;
        for (int i = t; i < EPB; i += 512) atomicAdd(&lds[((unsigned)erow[e0 + i]) >> 8], 1u);
        __syncthreads();
        for (int i = t; i < NBK; i += 512) cnt[bb * NBK + i] = lds[i];
    }
}

// ================ P2: hist reduce -> dinv (0..97) + bucket scan (98) + bnacc zero (99..130) ================
__global__ __launch_bounds__(256) void k_p2(const unsigned* __restrict__ Pcol,
                                            float* __restrict__ dinv,
                                            const unsigned* __restrict__ cnt,
                                            unsigned* __restrict__ off,
                                            unsigned* __restrict__ bstart,
                                            float* __restrict__ bnacc) {
    int t = threadIdx.x;
    if (blockIdx.x < 98) {
        int w = blockIdx.x * 256 + t;
        if (w >= HW) return;
        unsigned sc = 0;
        for (int b = 0; b < HG; b++) sc += Pcol[(size_t)b * HW + w];
        dinv[2 * w] = rsqrtf((float)((sc & 0xffffu) + 1u));
        dinv[2 * w + 1] = rsqrtf((float)((sc >> 16) + 1u));
    } else if (blockIdx.x == 98) {
        __shared__ unsigned s[256];
        unsigned tot = 0;
        if (t < NBK) for (int b = 0; b < PB; b++) tot += cnt[b * NBK + t];
        s[t] = tot;
        __syncthreads();
        for (int o = 1; o < 256; o <<= 1) {
            unsigned x = (t >= o) ? s[t - o] : 0u;
            __syncthreads();
            s[t] += x;
            __syncthreads();
        }
        unsigned base = s[t] - tot;
        if (t < NBK) bstart[t] = base;
        if (t == NBK - 1) bstart[NBK] = base + tot;
        if (t < NBK) {
            unsigned run = base;
            for (int b = 0; b < PB; b++) { off[b * NBK + t] = run; run += cnt[b * NBK + t]; }
        }
    } else {
        bnacc[(blockIdx.x - 99) * 256 + t] = 0.f;   // 32 blocks x 256 = 8192 floats
    }
}

// ================ P3: edge scatter into buckets (blocks 0..PB) + input prep (rest) ================
__global__ __launch_bounds__(256) void k_p3(const int* __restrict__ erow,
                                            const int* __restrict__ ecol,
                                            const unsigned* __restrict__ off,
                                            int2* __restrict__ ebuf,
                                            const float* __restrict__ x,
                                            const float* __restrict__ dinv,
                                            uchar* __restrict__ xs8,
                                            const float* __restrict__ W1,
                                            const float* __restrict__ W2,
                                            const float* __restrict__ W3,
                                            ushort* __restrict__ Wt1,
                                            ushort* __restrict__ Wt2,
                                            ushort* __restrict__ Wt3) {
    int t = threadIdx.x, b = blockIdx.x;
    if (b < PB) {
        __shared__ unsigned c[NBK];
        for (int i = t; i < NBK; i += 256) c[i] = off[b * NBK + i];
        __syncthreads();
        int e0 = b * EPB;
        for (int i = t; i < EPB; i += 256) {
            int r = erow[e0 + i], cc = ecol[e0 + i];
            unsigned p = atomicAdd(&c[((unsigned)r) >> 8], 1u);
            ebuf[p] = make_int2(r, cc);
        }
    } else if (b < PB + 6250) {
        int i = (b - PB) * 256 + t;   // over N*128/4 = 1.6M exactly
        int row = i >> 5;
        float d = dinv[row];
        float4 v = ((const float4*)x)[i];
        int p = fp8_enc_lo(v.x * d, v.y * d, 0);
        p = fp8_enc_hi(v.z * d, v.w * d, p);
        ((int*)xs8)[i] = p;
    } else {
        int i = (b - PB - 6250) * 256 + t;
        if (i < 128 * 256) { int k = i / 256, n = i % 256; Wt1[n * 128 + k] = f2bf(W1[i]); }
        if (i < 256 * 256) { int k = i / 256, n = i % 256; Wt2[n * 256 + k] = f2bf(W2[i]); }
        if (i < 48 * 256)  { int n = i / 256, k = i % 256;
                             Wt3[i] = (n < OUT_DIM) ? f2bf(W3[k * OUT_DIM + n]) : (ushort)0; }
    }
}

// ================ P4: per-bucket row counts -> rowptr -> colidx fill ================
__global__ __launch_bounds__(256) void k_part4(const int2* __restrict__ ebuf,
                                               const unsigned* __restrict__ bstart,
                                               unsigned* __restrict__ rowptr,
                                               int* __restrict__ colidx) {
    __shared__ unsigned rc[256], cur[256], s[256];
    int t = threadIdx.x, b = blockIdx.x;
    unsigned ebase = bstart[b], ecnt = bstart[b + 1] - ebase;
    rc[t] = 0u;
    __syncthreads();
    for (unsigned i = t; i < ecnt; i += 256) atomicAdd(&rc[ebuf[ebase + i].x & 255], 1u);
    __syncthreads();
    unsigned v = rc[t];
    s[t] = v;
    __syncthreads();
    for (int o = 1; o < 256; o <<= 1) {
        unsigned x = (t >= o) ? s[t - o] : 0u;
        __syncthreads();
        s[t] += x;
        __syncthreads();
    }
    unsigned excl = s[t] - v;
    int row = (b << 8) + t;
    if (row < NN) rowptr[row] = ebase + excl;
    cur[t] = ebase + excl;
    if (b == 0 && t == 0) rowptr[NN] = NE;
    __syncthreads();
    for (unsigned i = t; i < ecnt; i += 256) {
        int2 e = ebuf[ebase + i];
        unsigned p = atomicAdd(&cur[e.x & 255], 1u);
        colidx[p] = e.y;
    }
}

// ================ layer-1 aggregation: half-wave per edge, 2 edges in flight ================
// xs8 row = 128 fp8 = 32 uints; lane loads 1 uint (4 fp8).
__global__ __launch_bounds__(64) void k_agg_x(const uchar* __restrict__ xs8,
                                              const unsigned* __restrict__ rowptr,
                                              const int* __restrict__ colidx,
                                              const float* __restrict__ dinv,
                                              ushort* __restrict__ Xa) {
    int r = blockIdx.x;
    int t = threadIdx.x;
    int lane = t & 31, half = t >> 5;
    const unsigned* Xv = (const unsigned*)xs8;
    float a0 = 0.f, a1 = 0.f, a2 = 0.f, a3 = 0.f;
    if (half == 0) {
        unsigned y = Xv[(size_t)r * 32 + lane];
        f32x2 l = fp8_dec_lo((int)y), h = fp8_dec_hi((int)y);
        a0 = l[0]; a1 = l[1]; a2 = h[0]; a3 = h[1];
    }
    unsigned e0 = rowptr[r], e1 = rowptr[r + 1];
    unsigned e = e0 + half;
    for (; e + 6 < e1; e += 8) {
        int c0 = colidx[e], c1 = colidx[e + 2], c2 = colidx[e + 4], c3 = colidx[e + 6];
        unsigned v0 = Xv[(size_t)c0 * 32 + lane];
        unsigned v1 = Xv[(size_t)c1 * 32 + lane];
        unsigned v2 = Xv[(size_t)c2 * 32 + lane];
        unsigned v3 = Xv[(size_t)c3 * 32 + lane];
        f32x2 l0 = fp8_dec_lo((int)v0), h0 = fp8_dec_hi((int)v0);
        f32x2 l1 = fp8_dec_lo((int)v1), h1 = fp8_dec_hi((int)v1);
        f32x2 l2 = fp8_dec_lo((int)v2), h2 = fp8_dec_hi((int)v2);
        f32x2 l3 = fp8_dec_lo((int)v3), h3 = fp8_dec_hi((int)v3);
        a0 += l0[0] + l1[0] + l2[0] + l3[0];
        a1 += l0[1] + l1[1] + l2[1] + l3[1];
        a2 += h0[0] + h1[0] + h2[0] + h3[0];
        a3 += h0[1] + h1[1] + h2[1] + h3[1];
    }
    for (; e < e1; e += 2) {
        unsigned v = Xv[(size_t)colidx[e] * 32 + lane];
        f32x2 l = fp8_dec_lo((int)v), h = fp8_dec_hi((int)v);
        a0 += l[0]; a1 += l[1]; a2 += h[0]; a3 += h[1];
    }
    a0 += __shfl_xor(a0, 32, 64);
    a1 += __shfl_xor(a1, 32, 64);
    a2 += __shfl_xor(a2, 32, 64);
    a3 += __shfl_xor(a3, 32, 64);
    if (half == 0) {
        float dr = dinv[r];
        uint2 o;
        o.x = pack2bf(dr * a0, dr * a1);
        o.y = pack2bf(dr * a2, dr * a3);
        ((uint2*)Xa)[(size_t)r * 32 + lane] = o;   // 8 B/lane x 32 = 256 B row
    }
}

// ================ MFMA GEMM 1 (+fused BN1 column stats): H16 = Xa @ Wt1^T ================
template <int K>
__global__ __launch_bounds__(256) void k_gemm1(const ushort* __restrict__ A,
                                               const ushort* __restrict__ Bt,
                                               ushort* __restrict__ H16,
                                               float* __restrict__ bnacc) {
    constexpr int BK = 32;
    constexpr int LD = 40;
    __shared__ ushort sA[64 * LD];
    __shared__ ushort sB[128 * LD];
    int t = threadIdx.x;
    int wave = t >> 6, lane = t & 63;
    int quad = lane >> 4, m15 = lane & 15;
    long r0 = (long)blockIdx.x * 64;
    int n0 = blockIdx.y * 128;

    f32x4 acc[8];
#pragma unroll
    for (int i = 0; i < 8; i++) { acc[i][0] = 0.f; acc[i][1] = 0.f; acc[i][2] = 0.f; acc[i][3] = 0.f; }

    for (int k0 = 0; k0 < K; k0 += BK) {
        {
            int row = t >> 2, seg = (t & 3) * 8;
            long gr = r0 + row;
            uint4 v = make_uint4(0, 0, 0, 0);
            if (gr < NN) v = *(const uint4*)(A + gr * K + k0 + seg);
            *(uint4*)(sA + row * LD + seg) = v;
        }
        {
            int n = t >> 1, seg = (t & 1) * 16;
            const uint4* src = (const uint4*)(Bt + (long)(n0 + n) * K + k0 + seg);
            uint4 b0 = src[0], b1 = src[1];
            *(uint4*)(sB + n * LD + seg) = b0;
            *(uint4*)(sB + n * LD + seg + 8) = b1;
        }
        __syncthreads();
        short8 a = *(const short8*)(sA + (wave * 16 + m15) * LD + quad * 8);
#pragma unroll
        for (int ct = 0; ct < 8; ct++) {
            short8 b = *(const short8*)(sB + (ct * 16 + m15) * LD + quad * 8);
            acc[ct] = __builtin_amdgcn_mfma_f32_16x16x32_bf16(a, b, acc[ct], 0, 0, 0);
        }
        __syncthreads();
    }
    long rowbase = r0 + wave * 16 + quad * 4;
#pragma unroll
    for (int ct = 0; ct < 8; ct++) {
        int col = n0 + ct * 16 + m15;
#pragma unroll
        for (int rg = 0; rg < 4; rg++) {
            long gr = rowbase + rg;
            if (gr < NN) H16[gr * 256 + col] = f2bf(acc[ct][rg]);
        }
    }
    // ---- fused BN1 column stats (guard rows are exact zeros) ----
    float* ldsS = (float*)(void*)sA;
    float* ldsQ = (float*)(void*)sB;
#pragma unroll
    for (int ct = 0; ct < 8; ct++) {
        float s = acc[ct][0] + acc[ct][1] + acc[ct][2] + acc[ct][3];
        float q = acc[ct][0] * acc[ct][0] + acc[ct][1] * acc[ct][1]
                + acc[ct][2] * acc[ct][2] + acc[ct][3] * acc[ct][3];
        s += __shfl_xor(s, 16, 64); q += __shfl_xor(q, 16, 64);
        s += __shfl_xor(s, 32, 64); q += __shfl_xor(q, 32, 64);
        if (quad == 0) {
            ldsS[wave * 128 + ct * 16 + m15] = s;
            ldsQ[wave * 128 + ct * 16 + m15] = q;
        }
    }
    __syncthreads();
    {
        int c = t & 127;
        int slice = blockIdx.x & 7;
        float v = (t < 128)
            ? ldsS[c] + ldsS[128 + c] + ldsS[256 + c] + ldsS[384 + c]
            : ldsQ[c] + ldsQ[128 + c] + ldsQ[256 + c] + ldsQ[384 + c];
        atomicAdd(&bnacc[slice * 512 + ((t < 128) ? 0 : 256) + n0 + c], v);
    }
}

// BN scale/shift prologue: reduce 8 slices of bnacc into LDS (256 threads)
__device__ __forceinline__ void bn_prolog(const float* __restrict__ bnacc,
                                          const float* __restrict__ gamma,
                                          const float* __restrict__ beta,
                                          float* __restrict__ bnsc,
                                          float* __restrict__ bnsh, int t) {
    float s = 0.f, q = 0.f;
#pragma unroll
    for (int sl = 0; sl < 8; sl++) {
        s += bnacc[sl * 512 + t];
        q += bnacc[sl * 512 + 256 + t];
    }
    float mu = s * (1.f / NN);
    float var = q * (1.f / NN) - mu * mu;
    float g = gamma[t] * rsqrtf(var + BN_EPS);
    bnsc[t] = g;
    bnsh[t] = beta[t] - mu * g;
}

// BN+ReLU stage of 8 bf16 cols from H16 row into LDS (scale/shift from LDS)
__device__ __forceinline__ void bn_stage8(const ushort* __restrict__ Hrow, bool valid,
                                          const float* __restrict__ bnsc,
                                          const float* __restrict__ bnsh, int col0,
                                          ushort* __restrict__ dst) {
    uint4 hv = make_uint4(0, 0, 0, 0);
    if (valid) hv = *(const uint4*)(Hrow + col0);
    float f[8] = { bflo(hv.x), bfhi(hv.x), bflo(hv.y), bfhi(hv.y),
                   bflo(hv.z), bfhi(hv.z), bflo(hv.w), bfhi(hv.w) };
#pragma unroll
    for (int j = 0; j < 8; j++)
        dst[j] = f2bf(fmaxf(f[j] * bnsc[col0 + j] + bnsh[col0 + j], 0.f));
}

// ================ MFMA GEMM 2: Ys2(fp8, row-major) = fp8( dinv * (relu(bn(H16)) @ Wt2^T) ) ================
__global__ __launch_bounds__(256) void k_gemm2(const ushort* __restrict__ H16,
                                               const float* __restrict__ bnacc,
                                               const float* __restrict__ gamma,
                                               const float* __restrict__ beta,
                                               const ushort* __restrict__ Bt,
                                               const float* __restrict__ dinv,
                                               uchar* __restrict__ Y8) {
    constexpr int K = 256, BK = 32, LD = 40;
    __shared__ ushort sA[64 * LD];
    __shared__ ushort sB[128 * LD];
    __shared__ float bnsc[256], bnsh[256];
    int t = threadIdx.x;
    int wave = t >> 6, lane = t & 63;
    int quad = lane >> 4, m15 = lane & 15;
    long r0 = (long)blockIdx.x * 64;
    int n0 = blockIdx.y * 128;

    bn_prolog(bnacc, gamma, beta, bnsc, bnsh, t);
    __syncthreads();

    f32x4 acc[8];
#pragma unroll
    for (int i = 0; i < 8; i++) { acc[i][0] = 0.f; acc[i][1] = 0.f; acc[i][2] = 0.f; acc[i][3] = 0.f; }

    for (int k0 = 0; k0 < K; k0 += BK) {
        {
            int row = t >> 2, seg = (t & 3) * 8;
            long gr = r0 + row;
            bn_stage8(H16 + gr * 256, gr < NN, bnsc, bnsh, k0 + seg, sA + row * LD + seg);
        }
        {
            int n = t >> 1, seg = (t & 1) * 16;
            const uint4* src = (const uint4*)(Bt + (long)(n0 + n) * K + k0 + seg);
            uint4 b0 = src[0], b1 = src[1];
            *(uint4*)(sB + n * LD + seg) = b0;
            *(uint4*)(sB + n * LD + seg + 8) = b1;
        }
        __syncthreads();
        short8 a = *(const short8*)(sA + (wave * 16 + m15) * LD + quad * 8);
#pragma unroll
        for (int ct = 0; ct < 8; ct++) {
            short8 b = *(const short8*)(sB + (ct * 16 + m15) * LD + quad * 8);
            acc[ct] = __builtin_amdgcn_mfma_f32_16x16x32_bf16(a, b, acc[ct], 0, 0, 0);
        }
        __syncthreads();
    }
    long rowbase = r0 + wave * 16 + quad * 4;
    float dv[4];
#pragma unroll
    for (int rg = 0; rg < 4; rg++) dv[rg] = (rowbase + rg < NN) ? dinv[rowbase + rg] : 0.f;
#pragma unroll
    for (int ct = 0; ct < 8; ct++) {
        int col = n0 + ct * 16 + m15;
#pragma unroll
        for (int rg = 0; rg < 4; rg++) {
            long gr = rowbase + rg;
            if (gr < NN) {
                int p = fp8_enc_lo(dv[rg] * acc[ct][rg], 0.f, 0);
                Y8[gr * 256 + col] = (uchar)(p & 0xff);
            }
        }
    }
}

// ================ MFMA GEMM 3: Ys3 (stride 64, bf16) = dinv * (relu(bn2(H16)) @ Wt3^T) ================
__global__ __launch_bounds__(256) void k_gemm3(const ushort* __restrict__ H16,
                                               const float* __restrict__ bnacc,
                                               const float* __restrict__ gamma,
                                               const float* __restrict__ beta,
                                               const ushort* __restrict__ Wt3,
                                               const float* __restrict__ dinv,
                                               ushort* __restrict__ Y) {
    constexpr int LD = 264;
    __shared__ ushort sA[64 * LD];
    __shared__ ushort sB[48 * LD];
    __shared__ float bnsc[256], bnsh[256];
    int t = threadIdx.x;
    int wave = t >> 6, lane = t & 63;
    int quad = lane >> 4, m15 = lane & 15;
    long r0 = (long)blockIdx.x * 64;

    bn_prolog(bnacc, gamma, beta, bnsc, bnsh, t);
    __syncthreads();

    for (int idx = t; idx < 48 * 16; idx += 256) {
        int n = idx >> 4, s = (idx & 15) * 16;
        const uint4* src = (const uint4*)(Wt3 + n * 256 + s);
        *(uint4*)(sB + n * LD + s) = src[0];
        *(uint4*)(sB + n * LD + s + 8) = src[1];
    }
    {
        int row = t >> 2;
        long gr = r0 + row;
#pragma unroll
        for (int s8 = 0; s8 < 8; s8++) {
            int seg = s8 * 32 + (t & 3) * 8;
            bn_stage8(H16 + gr * 256, gr < NN, bnsc, bnsh, seg, sA + row * LD + seg);
        }
    }
    __syncthreads();

    f32x4 acc[3];
#pragma unroll
    for (int i = 0; i < 3; i++) { acc[i][0] = 0.f; acc[i][1] = 0.f; acc[i][2] = 0.f; acc[i][3] = 0.f; }
#pragma unroll
    for (int k0 = 0; k0 < 256; k0 += 32) {
        short8 a = *(const short8*)(sA + (wave * 16 + m15) * LD + k0 + quad * 8);
#pragma unroll
        for (int ct = 0; ct < 3; ct++) {
            short8 b = *(const short8*)(sB + (ct * 16 + m15) * LD + k0 + quad * 8);
            acc[ct] = __builtin_amdgcn_mfma_f32_16x16x32_bf16(a, b, acc[ct], 0, 0, 0);
        }
    }
    long rowbase = r0 + wave * 16 + quad * 4;
#pragma unroll
    for (int ct = 0; ct < 3; ct++) {
        int col = ct * 16 + m15;
#pragma unroll
        for (int rg = 0; rg < 4; rg++) {
            long gr = rowbase + rg;
            if (gr < NN) Y[gr * 64 + col] = f2bf(dinv[gr] * acc[ct][rg]);
        }
    }
}

// ================ layer-2 aggregation: half-wave per edge (uint2/lane), 2 edges in flight ================
// Y8 row = 256 fp8 = 32 uint2; lane loads 1 uint2 (8 fp8).
__global__ __launch_bounds__(64) void k_agg_hid(const uchar* __restrict__ Y8,
                                                const unsigned* __restrict__ rowptr,
                                                const int* __restrict__ colidx,
                                                const float* __restrict__ dinv,
                                                ushort* __restrict__ H16) {
    int r = blockIdx.x;
    int t = threadIdx.x;
    int lane = t & 31, half = t >> 5;
    const uint2* Yv = (const uint2*)Y8;
    float a0 = 0.f, a1 = 0.f, a2 = 0.f, a3 = 0.f, a4 = 0.f, a5 = 0.f, a6 = 0.f, a7 = 0.f;
    if (half == 0) {
        uint2 y = Yv[(size_t)r * 32 + lane];
        f32x2 p0 = fp8_dec_lo((int)y.x), p1 = fp8_dec_hi((int)y.x);
        f32x2 p2 = fp8_dec_lo((int)y.y), p3 = fp8_dec_hi((int)y.y);
        a0 = p0[0]; a1 = p0[1]; a2 = p1[0]; a3 = p1[1];
        a4 = p2[0]; a5 = p2[1]; a6 = p3[0]; a7 = p3[1];
    }
    unsigned e0 = rowptr[r], e1 = rowptr[r + 1];
    unsigned e = e0 + half;
    for (; e + 6 < e1; e += 8) {
        int c0 = colidx[e], c1 = colidx[e + 2], c2 = colidx[e + 4], c3 = colidx[e + 6];
        uint2 v0 = Yv[(size_t)c0 * 32 + lane];
        uint2 v1 = Yv[(size_t)c1 * 32 + lane];
        uint2 v2 = Yv[(size_t)c2 * 32 + lane];
        uint2 v3 = Yv[(size_t)c3 * 32 + lane];
        f32x2 l0x = fp8_dec_lo((int)v0.x), h0x = fp8_dec_hi((int)v0.x);
        f32x2 l0y = fp8_dec_lo((int)v0.y), h0y = fp8_dec_hi((int)v0.y);
        f32x2 l1x = fp8_dec_lo((int)v1.x), h1x = fp8_dec_hi((int)v1.x);
        f32x2 l1y = fp8_dec_lo((int)v1.y), h1y = fp8_dec_hi((int)v1.y);
        f32x2 l2x = fp8_dec_lo((int)v2.x), h2x = fp8_dec_hi((int)v2.x);
        f32x2 l2y = fp8_dec_lo((int)v2.y), h2y = fp8_dec_hi((int)v2.y);
        f32x2 l3x = fp8_dec_lo((int)v3.x), h3x = fp8_dec_hi((int)v3.x);
        f32x2 l3y = fp8_dec_lo((int)v3.y), h3y = fp8_dec_hi((int)v3.y);
        a0 += l0x[0] + l1x[0] + l2x[0] + l3x[0];
        a1 += l0x[1] + l1x[1] + l2x[1] + l3x[1];
        a2 += h0x[0] + h1x[0] + h2x[0] + h3x[0];
        a3 += h0x[1] + h1x[1] + h2x[1] + h3x[1];
        a4 += l0y[0] + l1y[0] + l2y[0] + l3y[0];
        a5 += l0y[1] + l1y[1] + l2y[1] + l3y[1];
        a6 += h0y[0] + h1y[0] + h2y[0] + h3y[0];
        a7 += h0y[1] + h1y[1] + h2y[1] + h3y[1];
    }
    for (; e < e1; e += 2) {
        uint2 v = Yv[(size_t)colidx[e] * 32 + lane];
        f32x2 lx = fp8_dec_lo((int)v.x), hx = fp8_dec_hi((int)v.x);
        f32x2 ly = fp8_dec_lo((int)v.y), hy = fp8_dec_hi((int)v.y);
        a0 += lx[0]; a1 += lx[1]; a2 += hx[0]; a3 += hx[1];
        a4 += ly[0]; a5 += ly[1]; a6 += hy[0]; a7 += hy[1];
    }
    a0 += __shfl_xor(a0, 32, 64); a1 += __shfl_xor(a1, 32, 64);
    a2 += __shfl_xor(a2, 32, 64); a3 += __shfl_xor(a3, 32, 64);
    a4 += __shfl_xor(a4, 32, 64); a5 += __shfl_xor(a5, 32, 64);
    a6 += __shfl_xor(a6, 32, 64); a7 += __shfl_xor(a7, 32, 64);
    if (half == 0) {
        float dr = dinv[r];
        uint4 o;
        o.x = pack2bf(dr * a0, dr * a1);
        o.y = pack2bf(dr * a2, dr * a3);
        o.z = pack2bf(dr * a4, dr * a5);
        o.w = pack2bf(dr * a6, dr * a7);
        ((uint4*)H16)[(size_t)r * 32 + lane] = o;   // 16 B/lane x 32 = 512 B row
    }
}

// ================ layer-3 aggregation + bias + log_softmax (half-wave) ================
// Ys3 row = 64 bf16 (stride 64) = 32 uints; lane covers cols 2*lane, 2*lane+1.
__global__ __launch_bounds__(64) void k_agg_lsm(const ushort* __restrict__ Y,
                                                const unsigned* __restrict__ rowptr,
                                                const int* __restrict__ colidx,
                                                const float* __restrict__ dinv,
                                                const float* __restrict__ b3,
                                                float* __restrict__ out) {
    int r = blockIdx.x;
    int t = threadIdx.x;
    int lane = t & 31, half = t >> 5;
    const unsigned* Yv = (const unsigned*)Y;
    float a0 = 0.f, a1 = 0.f;
    if (half == 0) {
        unsigned y = Yv[(size_t)r * 32 + lane];
        a0 = bflo(y); a1 = bfhi(y);
    }
    unsigned e0 = rowptr[r], e1 = rowptr[r + 1];
    unsigned e = e0 + half;
    for (; e + 6 < e1; e += 8) {
        int c0 = colidx[e], c1 = colidx[e + 2], c2 = colidx[e + 4], c3 = colidx[e + 6];
        unsigned v0 = Yv[(size_t)c0 * 32 + lane];
        unsigned v1 = Yv[(size_t)c1 * 32 + lane];
        unsigned v2 = Yv[(size_t)c2 * 32 + lane];
        unsigned v3 = Yv[(size_t)c3 * 32 + lane];
        a0 += bflo(v0) + bflo(v1) + bflo(v2) + bflo(v3);
        a1 += bfhi(v0) + bfhi(v1) + bfhi(v2) + bfhi(v3);
    }
    for (; e < e1; e += 2) {
        unsigned v = Yv[(size_t)colidx[e] * 32 + lane];
        a0 += bflo(v); a1 += bfhi(v);
    }
    a0 += __shfl_xor(a0, 32, 64);
    a1 += __shfl_xor(a1, 32, 64);
    bool act = (half == 0) && (lane < OUT_DIM / 2);
    float o0 = -1e30f, o1 = -1e30f;
    if (act) {
        float dr = dinv[r];
        o0 = dr * a0 + b3[2 * lane];
        o1 = dr * a1 + b3[2 * lane + 1];
    }
    float m = fmaxf(o0, o1);
#pragma unroll
    for (int d = 1; d < 64; d <<= 1) m = fmaxf(m, __shfl_xor(m, d, 64));
    float ex = act ? (expf(o0 - m) + expf(o1 - m)) : 0.f;
#pragma unroll
    for (int d = 1; d < 64; d <<= 1) ex += __shfl_xor(ex, d, 64);
    float ls = logf(ex) + m;
    if (act) {
        out[(size_t)r * OUT_DIM + 2 * lane] = o0 - ls;
        out[(size_t)r * OUT_DIM + 2 * lane + 1] = o1 - ls;
    }
}

// ================ fast BN stats for layer 2 (uint4 loads, LDS reduce, slice atomics) ================
__global__ __launch_bounds__(256) void k_bn_stats2(const ushort* __restrict__ H16,
                                                   float* __restrict__ bnacc) {
    __shared__ float ls[512];
    int t = threadIdx.x;
    ls[t] = 0.f; ls[t + 256] = 0.f;
    __syncthreads();
    int colb = (t & 31) * 8;
    float s[8], q[8];
#pragma unroll
    for (int j = 0; j < 8; j++) { s[j] = 0.f; q[j] = 0.f; }
    for (int rb = blockIdx.x * 8 + (t >> 5); rb < NN; rb += gridDim.x * 8) {
        uint4 v = *(const uint4*)(H16 + (size_t)rb * 256 + colb);
        float f[8] = { bflo(v.x), bfhi(v.x), bflo(v.y), bfhi(v.y),
                       bflo(v.z), bfhi(v.z), bflo(v.w), bfhi(v.w) };
#pragma unroll
        for (int j = 0; j < 8; j++) { s[j] += f[j]; q[j] += f[j] * f[j]; }
    }
#pragma unroll
    for (int j = 0; j < 8; j++) {
        atomicAdd(&ls[colb + j], s[j]);
        atomicAdd(&ls[256 + colb + j], q[j]);
    }
    __syncthreads();
    int slice = blockIdx.x & 7;
    atomicAdd(&bnacc[slice * 512 + t], ls[t]);
    atomicAdd(&bnacc[slice * 512 + 256 + t], ls[t + 256]);
}

// ================ launch ================

extern "C" void kernel_launch(void* const* d_in, const int* in_sizes, int n_in,
                              void* d_out, int out_size, void* d_ws, size_t ws_size,
                              hipStream_t stream) {
    const float* x     = (const float*)d_in[0];
    const int*   erow  = (const int*)d_in[1];
    const int*   ecol  = ((const int*)d_in[1]) + NE;
    const float* W1    = (const float*)d_in[2];
    const float* W2    = (const float*)d_in[4];
    const float* W3    = (const float*)d_in[6];
    const float* b3    = (const float*)d_in[7];
    const float* gamma = (const float*)d_in[8];
    const float* beta  = (const float*)d_in[9];
    float* out = (float*)d_out;

    char* ws = (char*)d_ws;
    size_t off = 0;
    auto alloc = [&](size_t bytes) -> void* {
        void* p = ws + off;
        off = (off + bytes + 255) & ~(size_t)255;
        return p;
    };
    float*    dinv     = (float*)alloc(NN * 4);
    unsigned* rowptr   = (unsigned*)alloc((NN + 1) * 4);
    int*      colidx   = (int*)alloc((size_t)NE * 4);
    float*    bnacc    = (float*)alloc(2 * 8 * 512 * 4);   // [0]=layer1, [1]=layer2
    unsigned* cnt      = (unsigned*)alloc((size_t)PB * NBK * 4);
    unsigned* boff     = (unsigned*)alloc((size_t)PB * NBK * 4);
    unsigned* bstart   = (unsigned*)alloc((NBK + 1) * 4);
    ushort*   Wt1      = (ushort*)alloc(128 * 256 * 2);
    ushort*   Wt2      = (ushort*)alloc(256 * 256 * 2);
    ushort*   Wt3      = (ushort*)alloc(48 * 256 * 2);
    uchar*    xs8      = (uchar*)alloc((size_t)NN * IN_DIM);       // fp8 dinv-scaled x, row-major
    ushort*   Xa       = (ushort*)alloc((size_t)NN * IN_DIM * 2);  // aggregated x, bf16
    ushort*   H16      = (ushort*)alloc((size_t)NN * HID * 2);     // conv output, bf16
    uchar*    Ys2      = (uchar*)alloc((size_t)NN * HID);          // fp8 layer-2 transform, row-major
    ushort*   Ys3      = (ushort*)alloc((size_t)NN * 64 * 2);      // bf16 layer-3 transform

    float* bnacc1 = bnacc;
    float* bnacc2 = bnacc + 8 * 512;

    // aliases into H16 (25.6 MB), dead before gemm1 writes H16:
    unsigned* Pcol = (unsigned*)H16;                                   // 12.8 MB
    int2*     ebuf = (int2*)((char*)H16 + (size_t)13 * 1024 * 1024);   // 6.4 MB

    // --- preprocessing (bnacc zeroed inside k_p2) ---
    k_p1<<<HG + PB, 512, 0, stream>>>(erow, ecol, Pcol, cnt);
    k_p2<<<99 + 32, 256, 0, stream>>>(Pcol, dinv, cnt, boff, bstart, bnacc);
    k_p3<<<PB + 6250 + 256, 256, 0, stream>>>(erow, ecol, boff, ebuf,
                                              x, dinv, xs8, W1, W2, W3, Wt1, Wt2, Wt3);
    k_part4<<<NBK, 256, 0, stream>>>(ebuf, bstart, rowptr, colidx);

    dim3 ggrid((NN + 63) / 64, 2);

    // --- layer 1: fp8 half-wave gather, transform + fused BN1 stats ---
    k_agg_x<<<NN, 64, 0, stream>>>(xs8, rowptr, colidx, dinv, Xa);
    k_gemm1<IN_DIM><<<ggrid, 256, 0, stream>>>(Xa, Wt1, H16, bnacc1);

    // --- layer 2: BN1 prologue + fused staging; fp8 row-major output table ---
    k_gemm2<<<ggrid, 256, 0, stream>>>(H16, bnacc1, gamma, beta, Wt2, dinv, Ys2);
    k_agg_hid<<<NN, 64, 0, stream>>>(Ys2, rowptr, colidx, dinv, H16);
    k_bn_stats2<<<1024, 256, 0, stream>>>(H16, bnacc2);

    // --- layer 3: BN2 prologue in gemm3 ---
    k_gemm3<<<(NN + 63) / 64, 256, 0, stream>>>(H16, bnacc2, gamma, beta, Wt3, dinv, Ys3);
    k_agg_lsm<<<NN, 64, 0, stream>>>(Ys3, rowptr, colidx, dinv, b3, out);
}